// Round 13
// baseline (265.050 us; speedup 1.0000x reference)
//
#include <hip/hip_runtime.h>
#include <hip/hip_bf16.h>

#define E_ 2048
#define S_ 2048
#define B_ 2
#define BS_ 4096
#define KV_ 512
#define NH_ 16
#define G_ 4
#define HD_ 128
#define QK_SCALE 0.08838834764831845f
#define LOG2E_ 1.4426950408889634f

typedef __attribute__((ext_vector_type(8))) short short8;
typedef __attribute__((ext_vector_type(4))) float floatx4;
typedef __attribute__((ext_vector_type(4))) unsigned short ushort4_;

static __device__ __forceinline__ unsigned short f2bf(float f) {
  unsigned int u = __builtin_bit_cast(unsigned int, f);
  u += 0x7fffu + ((u >> 16) & 1u);
  return (unsigned short)(u >> 16);
}

static __device__ __forceinline__ unsigned int cvt_pk_bf16(float lo, float hi) {
  unsigned int r;
  asm("v_cvt_pk_bf16_f32 %0, %1, %2" : "=v"(r) : "v"(lo), "v"(hi));
  return r;
}

static __device__ __forceinline__ void gld16(const void* g, void* l) {
  __builtin_amdgcn_global_load_lds(
      (const __attribute__((address_space(1))) unsigned int*)g,
      (__attribute__((address_space(3))) unsigned int*)l, 16, 0, 0);
}

// ---------------- prep: 4 weight transposes (fp32 [K][N] -> bf16 [N][K]) -------------
__global__ __launch_bounds__(256) void k_prep(
    const float* __restrict__ Wq, unsigned short* __restrict__ WqT,
    const float* __restrict__ Wk, unsigned short* __restrict__ WkT,
    const float* __restrict__ Wv, unsigned short* __restrict__ WvT,
    const float* __restrict__ Wo, unsigned short* __restrict__ WoT) {
  __shared__ float ts[32][33];
  int t = blockIdx.x;
  const float* in; unsigned short* out; int N; int rem;
  if (t < 4096)      { in = Wq; out = WqT; N = 2048; rem = t; }
  else if (t < 5120) { in = Wk; out = WkT; N = 512;  rem = t - 4096; }
  else if (t < 6144) { in = Wv; out = WvT; N = 512;  rem = t - 5120; }
  else               { in = Wo; out = WoT; N = 2048; rem = t - 6144; }
  const int K = 2048;
  int nx = N >> 5;
  int bx = rem % nx, by = rem / nx;
  int tx = threadIdx.x & 31, ty = threadIdx.x >> 5;
  int n0 = bx * 32, k0 = by * 32;
#pragma unroll
  for (int i = 0; i < 4; ++i)
    ts[ty + i * 8][tx] = in[(size_t)(k0 + ty + i * 8) * N + n0 + tx];
  __syncthreads();
#pragma unroll
  for (int i = 0; i < 4; ++i)
    out[(size_t)(n0 + ty + i * 8) * K + k0 + tx] = f2bf(ts[tx][ty + i * 8]);
}

// ------- bt-GEMM tile body (BK=32, double-buffered, 1 barrier / K-step) -------------
// A_F32 / B_F32: that operand is fp32 in global; reg-stage with fused cvt to bf16.
template <bool OUT_F32, bool A_F32, bool B_F32>
static __device__ __forceinline__ void gemm_bt_tile(
    const void* __restrict__ A, const void* __restrict__ Bt,
    const float* __restrict__ bias, bool rowBias, void* __restrict__ C,
    int N, int K, float scale, int bx, int by,
    unsigned short* As, unsigned short* Bs) {
  const int tid = threadIdx.x;
  const int w = tid >> 6;
  const int lhi = (tid >> 4) & 3;
  const int llo = tid & 15;
  const int wr = w >> 1, wc = w & 1;
  const size_t brow = (size_t)by * 128, bcol = (size_t)bx * 128;

  auto stage = [&](int k0, int bufi) {
#pragma unroll
    for (int i = 0; i < 2; ++i) {
      int o = i * 256 + tid;
      if constexpr (A_F32) {
        int row = o >> 2, gcol = o & 3;
        const float4* src = reinterpret_cast<const float4*>(
            (const float*)A + (brow + row) * (size_t)K + k0 + gcol * 8);
        float4 v0 = src[0], v1 = src[1];
        uint4 pk = {cvt_pk_bf16(v0.x, v0.y), cvt_pk_bf16(v0.z, v0.w),
                    cvt_pk_bf16(v1.x, v1.y), cvt_pk_bf16(v1.z, v1.w)};
        *reinterpret_cast<uint4*>(As + bufi * 4096 + (size_t)o * 8) = pk;
      } else {
        gld16((const unsigned short*)A + (brow + (o >> 2)) * (size_t)K + k0 + (o & 3) * 8,
              As + bufi * 4096 + (size_t)(i * 256 + w * 64) * 8);
      }
      if constexpr (B_F32) {
        int row = o >> 2, gcol = o & 3;
        const float4* src = reinterpret_cast<const float4*>(
            (const float*)Bt + (bcol + row) * (size_t)K + k0 + gcol * 8);
        float4 v0 = src[0], v1 = src[1];
        uint4 pk = {cvt_pk_bf16(v0.x, v0.y), cvt_pk_bf16(v0.z, v0.w),
                    cvt_pk_bf16(v1.x, v1.y), cvt_pk_bf16(v1.z, v1.w)};
        *reinterpret_cast<uint4*>(Bs + bufi * 4096 + (size_t)o * 8) = pk;
      } else {
        gld16((const unsigned short*)Bt + (bcol + (o >> 2)) * (size_t)K + k0 + (o & 3) * 8,
              Bs + bufi * 4096 + (size_t)(i * 256 + w * 64) * 8);
      }
    }
  };

  floatx4 acc[4][4];
#pragma unroll
  for (int i = 0; i < 4; ++i)
#pragma unroll
    for (int j = 0; j < 4; ++j)
      acc[i][j] = (floatx4){0.f, 0.f, 0.f, 0.f};

  stage(0, 0);
  __syncthreads();
  int buf = 0;
  const int nk = K >> 5;
  for (int t = 0; t < nk; ++t) {
    if (t + 1 < nk) stage((t + 1) * 32, buf ^ 1);
    const unsigned short* Ab = As + buf * 4096;
    const unsigned short* Bb = Bs + buf * 4096;
    short8 a[4], b[4];
#pragma unroll
    for (int f = 0; f < 4; ++f) {
      a[f] = *reinterpret_cast<const short8*>(Ab + (wr * 64 + f * 16 + llo) * 32 + lhi * 8);
      b[f] = *reinterpret_cast<const short8*>(Bb + (wc * 64 + f * 16 + llo) * 32 + lhi * 8);
    }
    __builtin_amdgcn_s_setprio(1);
#pragma unroll
    for (int i = 0; i < 4; ++i)
#pragma unroll
      for (int j = 0; j < 4; ++j)
        acc[i][j] = __builtin_amdgcn_mfma_f32_16x16x32_bf16(a[i], b[j], acc[i][j], 0, 0, 0);
    __builtin_amdgcn_s_setprio(0);
    __syncthreads();
    buf ^= 1;
  }

#pragma unroll
  for (int i = 0; i < 4; ++i) {
#pragma unroll
    for (int j = 0; j < 4; ++j) {
      size_t gr0 = brow + wr * 64 + i * 16 + lhi * 4;
      size_t gc = bcol + wc * 64 + j * 16 + llo;
#pragma unroll
      for (int r = 0; r < 4; ++r) {
        size_t grow = gr0 + r;
        float v = acc[i][j][r];
        v += rowBias ? bias[grow] : bias[gc];
        v *= scale;
        if (OUT_F32)
          ((float*)C)[grow * N + gc] = v;
        else
          ((unsigned short*)C)[grow * N + gc] = f2bf(v);
      }
    }
  }
}

// fused Q + K + V projections; fp32 activations converted in-staging.
// Simple PANEL-MAJOR order: consecutive bids share one activation row-panel
// (cols walk fastest) so each fp32 panel stays L3-resident across its use window.
__global__ __launch_bounds__(256) void k_gemm_qkv(
    const float* __restrict__ query, const unsigned short* __restrict__ WqT,
    const float* __restrict__ bq, unsigned short* __restrict__ qb,
    const float* __restrict__ key_in, const unsigned short* __restrict__ WkT,
    const float* __restrict__ bk, unsigned short* __restrict__ kb,
    const unsigned short* __restrict__ WvT, const float* __restrict__ value,
    const float* __restrict__ bv, unsigned short* __restrict__ vtb) {
  __shared__ __align__(16) unsigned short As[2 * 128 * 32];
  __shared__ __align__(16) unsigned short Bs[2 * 128 * 32];
  int bid = blockIdx.x;
  if (bid < 512) {
    int by = bid >> 4;                 // activation row-panel (slow)
    int bx = bid & 15;                 // weight cols (fast)
    gemm_bt_tile<false, true, false>(query, WqT, bq, false, qb, E_, E_,
                                     QK_SCALE * LOG2E_, bx, by, As, Bs);
  } else if (bid < 640) {
    int u = bid - 512;
    int by = u >> 2;                   // activation row-panel (slow)
    int bx = u & 3;
    gemm_bt_tile<false, true, false>(key_in, WkT, bk, false, kb, KV_, E_, 1.0f,
                                     bx, by, As, Bs);
  } else {
    int u = bid - 640;
    int bx = u >> 2;                   // activation panel is the B operand (slow)
    int by = u & 3;
    gemm_bt_tile<false, false, true>(WvT, value, bv, true, vtb, BS_, E_, 1.0f,
                                     bx, by, As, Bs);
  }
}

__global__ __launch_bounds__(256) void k_gemm_o(
    const unsigned short* __restrict__ A, const unsigned short* __restrict__ Bt,
    const float* __restrict__ bias, float* __restrict__ C) {
  __shared__ __align__(16) unsigned short As[2 * 128 * 32];
  __shared__ __align__(16) unsigned short Bs[2 * 128 * 32];
  int by = blockIdx.x >> 4;            // attb row-panel (slow)
  int bx = blockIdx.x & 15;
  gemm_bt_tile<true, false, false>(A, Bt, bias, false, C, E_, E_, 1.0f,
                                   bx, by, As, Bs);
}

// ---------------- fused GQA flash attention (QBLK=256, 8 waves, K+V dbuf in LDS) -----
// XCD-affinity swizzle: bid%8 selects (b,g) so each XCD's L2 owns ONE KV working set.
__global__ __launch_bounds__(512) void k_attn(
    const unsigned short* __restrict__ qb, const unsigned short* __restrict__ kb,
    const unsigned short* __restrict__ vt, unsigned short* __restrict__ attn) {
  __shared__ __align__(16) unsigned short Ks[2][64 * 128];
  __shared__ __align__(16) unsigned short Vs[2][128 * 64];
  __shared__ __align__(16) unsigned short Ps[8][32 * 64];

  const int tid = threadIdx.x;
  const int w = tid >> 6;
  const int lhi = (tid >> 4) & 3;
  const int llo = tid & 15;
  const int bid = blockIdx.x;
  const int xcd = bid & 7;
  const int b = xcd >> 2, g = xcd & 3;
  const int inner = bid >> 3;
  const int hq = inner & 3, qt = inner >> 2;
  const int h = g * 4 + hq;

  char* PsW = (char*)&Ps[0][0] + w * 4096;

  short8 qf[2][4];
#pragma unroll
  for (int rt = 0; rt < 2; ++rt)
#pragma unroll
    for (int hc = 0; hc < 4; ++hc) {
      int row = qt * 256 + w * 32 + rt * 16 + llo;
      qf[rt][hc] = *reinterpret_cast<const short8*>(
          qb + ((size_t)(b * 2048 + row)) * 2048 + h * 128 + hc * 32 + lhi * 8);
    }

  floatx4 acc[2][8];
#pragma unroll
  for (int rt = 0; rt < 2; ++rt)
#pragma unroll
    for (int dc = 0; dc < 8; ++dc)
      acc[rt][dc] = (floatx4){0.f, 0.f, 0.f, 0.f};
  float m_[2] = {-1e30f, -1e30f};
  float l_[2] = {0.f, 0.f};

  auto stage = [&](int kv0, int buf) {
#pragma unroll
    for (int i = 0; i < 2; ++i) {
      int o = i * 512 + tid;
      int row = o >> 4, gr2 = (o & 15) ^ (row & 7);
      gld16(kb + ((size_t)(b * 2048 + kv0 + row)) * 512 + g * 128 + gr2 * 8,
            &Ks[buf][(size_t)(i * 512 + w * 64) * 8]);
    }
#pragma unroll
    for (int i = 0; i < 2; ++i) {
      int o = i * 512 + tid;
      int row = o >> 3, gr2 = (o & 7) ^ (row & 7);
      gld16(vt + ((size_t)(g * 128 + row)) * 4096 + b * 2048 + kv0 + gr2 * 8,
            &Vs[buf][(size_t)(i * 512 + w * 64) * 8]);
    }
  };

  stage(0, 0);
  __syncthreads();
  int buf = 0;

  for (int t = 0; t < 32; ++t) {
    const int kv0 = t * 64;
    if (t < 31) stage(kv0 + 64, buf ^ 1);

    floatx4 sc[2][4];
#pragma unroll
    for (int rt = 0; rt < 2; ++rt)
#pragma unroll
      for (int c = 0; c < 4; ++c)
        sc[rt][c] = (floatx4){0.f, 0.f, 0.f, 0.f};
    __builtin_amdgcn_s_setprio(1);
#pragma unroll
    for (int c = 0; c < 4; ++c) {
      int krow = c * 16 + llo;
#pragma unroll
      for (int hc = 0; hc < 4; ++hc) {
        int byteoff = krow * 256 + ((hc * 64 + lhi * 16) ^ ((krow & 7) << 4));
        short8 kf = *reinterpret_cast<const short8*>((const char*)&Ks[buf][0] + byteoff);
        sc[0][c] = __builtin_amdgcn_mfma_f32_16x16x32_bf16(kf, qf[0][hc], sc[0][c], 0, 0, 0);
        sc[1][c] = __builtin_amdgcn_mfma_f32_16x16x32_bf16(kf, qf[1][hc], sc[1][c], 0, 0, 0);
      }
    }
    __builtin_amdgcn_s_setprio(0);

#pragma unroll
    for (int rt = 0; rt < 2; ++rt) {
      float pm = sc[rt][0][0];
#pragma unroll
      for (int c = 0; c < 4; ++c)
#pragma unroll
        for (int r = 0; r < 4; ++r) pm = fmaxf(pm, sc[rt][c][r]);
      if (__any(pm > m_[rt] + 8.0f)) {
        float t2 = pm;
        t2 = fmaxf(t2, __shfl_xor(t2, 16));
        t2 = fmaxf(t2, __shfl_xor(t2, 32));
        float m2 = fmaxf(m_[rt], t2);
        float scr = __builtin_amdgcn_exp2f(m_[rt] - m2);
        m_[rt] = m2;
        l_[rt] *= scr;
#pragma unroll
        for (int r = 0; r < 4; ++r) {
          float s_r = __shfl(scr, (tid & 48) | (((tid >> 2) & 12) + r));
#pragma unroll
          for (int dc = 0; dc < 8; ++dc) acc[rt][dc][r] *= s_r;
        }
      }
      float lsum = l_[rt];
#pragma unroll
      for (int c = 0; c < 4; ++c) {
        float e0 = __builtin_amdgcn_exp2f(sc[rt][c][0] - m_[rt]);
        float e1 = __builtin_amdgcn_exp2f(sc[rt][c][1] - m_[rt]);
        float e2 = __builtin_amdgcn_exp2f(sc[rt][c][2] - m_[rt]);
        float e3 = __builtin_amdgcn_exp2f(sc[rt][c][3] - m_[rt]);
        lsum += (e0 + e1) + (e2 + e3);
        uint2 pk;
        pk.x = cvt_pk_bf16(e0, e1);
        pk.y = cvt_pk_bf16(e2, e3);
        int byteoff = (rt * 16 + llo) * 128 + ((c * 32 + lhi * 8) ^ ((llo & 7) << 4));
        *reinterpret_cast<uint2*>(PsW + byteoff) = pk;
      }
      l_[rt] = lsum;
    }

    short8 pf[2][2];
#pragma unroll
    for (int rt = 0; rt < 2; ++rt)
#pragma unroll
      for (int kc = 0; kc < 2; ++kc) {
        int byteoff = (rt * 16 + llo) * 128 + ((kc * 64 + lhi * 16) ^ ((llo & 7) << 4));
        pf[rt][kc] = *reinterpret_cast<const short8*>(PsW + byteoff);
      }
    __builtin_amdgcn_s_setprio(1);
#pragma unroll
    for (int dc = 0; dc < 8; ++dc) {
      int vrow = dc * 16 + llo;
      int bo0 = vrow * 128 + ((lhi * 16) ^ ((vrow & 7) << 4));
      int bo1 = vrow * 128 + ((64 + lhi * 16) ^ ((vrow & 7) << 4));
      short8 vf0 = *reinterpret_cast<const short8*>((const char*)&Vs[buf][0] + bo0);
      short8 vf1 = *reinterpret_cast<const short8*>((const char*)&Vs[buf][0] + bo1);
      acc[0][dc] = __builtin_amdgcn_mfma_f32_16x16x32_bf16(pf[0][0], vf0, acc[0][dc], 0, 0, 0);
      acc[1][dc] = __builtin_amdgcn_mfma_f32_16x16x32_bf16(pf[1][0], vf0, acc[1][dc], 0, 0, 0);
      acc[0][dc] = __builtin_amdgcn_mfma_f32_16x16x32_bf16(pf[0][1], vf1, acc[0][dc], 0, 0, 0);
      acc[1][dc] = __builtin_amdgcn_mfma_f32_16x16x32_bf16(pf[1][1], vf1, acc[1][dc], 0, 0, 0);
    }
    __builtin_amdgcn_s_setprio(0);
    __syncthreads();
    buf ^= 1;
  }

#pragma unroll
  for (int rt = 0; rt < 2; ++rt) {
    float t2 = l_[rt];
    t2 += __shfl_xor(t2, 16);
    t2 += __shfl_xor(t2, 32);
    float linv = 1.0f / t2;
    float lr[4];
#pragma unroll
    for (int r = 0; r < 4; ++r)
      lr[r] = __shfl(linv, (tid & 48) | (((tid >> 2) & 12) + r));
#pragma unroll
    for (int dc = 0; dc < 8; ++dc)
#pragma unroll
      for (int r = 0; r < 4; ++r) {
        int row = qt * 256 + w * 32 + rt * 16 + lhi * 4 + r;
        float v = acc[rt][dc][r] * lr[r];
        attn[((size_t)(b * 2048 + row)) * 2048 + h * 128 + dc * 16 + llo] = f2bf(v);
      }
  }
}

extern "C" void kernel_launch(void* const* d_in, const int* in_sizes, int n_in,
                              void* d_out, int out_size, void* d_ws, size_t ws_size,
                              hipStream_t stream) {
  const float* query  = (const float*)d_in[0];
  const float* key_in = (const float*)d_in[1];
  const float* value  = (const float*)d_in[2];
  const float* Wq = (const float*)d_in[3];
  const float* bq = (const float*)d_in[4];
  const float* Wk = (const float*)d_in[5];
  const float* bk = (const float*)d_in[6];
  const float* Wv = (const float*)d_in[7];
  const float* bv = (const float*)d_in[8];
  const float* Wo = (const float*)d_in[9];
  const float* bo = (const float*)d_in[10];
  float* out = (float*)d_out;

  char* ws = (char*)d_ws;
  size_t off = 0;
  auto alloc = [&](size_t bytes) {
    char* p = ws + off;
    off += (bytes + 255) & ~(size_t)255;
    return p;
  };
  unsigned short* WqT  = (unsigned short*)alloc((size_t)E_ * E_ * 2);
  unsigned short* WkT  = (unsigned short*)alloc((size_t)KV_ * E_ * 2);
  unsigned short* WvT  = (unsigned short*)alloc((size_t)KV_ * E_ * 2);
  unsigned short* WoT  = (unsigned short*)alloc((size_t)E_ * E_ * 2);
  unsigned short* qb   = (unsigned short*)alloc((size_t)BS_ * E_ * 2);
  unsigned short* kb   = (unsigned short*)alloc((size_t)BS_ * KV_ * 2);
  unsigned short* vtb  = (unsigned short*)alloc((size_t)KV_ * BS_ * 2);
  unsigned short* attb = (unsigned short*)alloc((size_t)BS_ * E_ * 2);

  k_prep<<<10240, 256, 0, stream>>>(Wq, WqT, Wk, WkT, Wv, WvT, Wo, WoT);
  k_gemm_qkv<<<768, 256, 0, stream>>>(query, WqT, bq, qb, key_in, WkT, bk, kb,
                                      WvT, value, bv, vtb);
  k_attn<<<B_ * NH_ * (S_ / 256), 512, 0, stream>>>(qb, kb, vtb, attb);
  k_gemm_o<<<512, 256, 0, stream>>>(attb, WoT, bo, out);
}

// Round 14
// 232.777 us; speedup vs baseline: 1.1386x; 1.1386x over previous
//
#include <hip/hip_runtime.h>
#include <hip/hip_bf16.h>

#define E_ 2048
#define S_ 2048
#define B_ 2
#define BS_ 4096
#define KV_ 512
#define NH_ 16
#define G_ 4
#define HD_ 128
#define QK_SCALE 0.08838834764831845f
#define LOG2E_ 1.4426950408889634f

typedef __attribute__((ext_vector_type(8))) short short8;
typedef __attribute__((ext_vector_type(4))) float floatx4;
typedef __attribute__((ext_vector_type(4))) unsigned short ushort4_;

static __device__ __forceinline__ unsigned short f2bf(float f) {
  unsigned int u = __builtin_bit_cast(unsigned int, f);
  u += 0x7fffu + ((u >> 16) & 1u);
  return (unsigned short)(u >> 16);
}

static __device__ __forceinline__ unsigned int cvt_pk_bf16(float lo, float hi) {
  unsigned int r;
  asm("v_cvt_pk_bf16_f32 %0, %1, %2" : "=v"(r) : "v"(lo), "v"(hi));
  return r;
}

static __device__ __forceinline__ void gld16(const void* g, void* l) {
  __builtin_amdgcn_global_load_lds(
      (const __attribute__((address_space(1))) unsigned int*)g,
      (__attribute__((address_space(3))) unsigned int*)l, 16, 0, 0);
}

// ---------------- prep: 4 weight transposes (fp32 [K][N] -> bf16 [N][K]) -------------
__global__ __launch_bounds__(256) void k_prep(
    const float* __restrict__ Wq, unsigned short* __restrict__ WqT,
    const float* __restrict__ Wk, unsigned short* __restrict__ WkT,
    const float* __restrict__ Wv, unsigned short* __restrict__ WvT,
    const float* __restrict__ Wo, unsigned short* __restrict__ WoT) {
  __shared__ float ts[32][33];
  int t = blockIdx.x;
  const float* in; unsigned short* out; int N; int rem;
  if (t < 4096)      { in = Wq; out = WqT; N = 2048; rem = t; }
  else if (t < 5120) { in = Wk; out = WkT; N = 512;  rem = t - 4096; }
  else if (t < 6144) { in = Wv; out = WvT; N = 512;  rem = t - 5120; }
  else               { in = Wo; out = WoT; N = 2048; rem = t - 6144; }
  const int K = 2048;
  int nx = N >> 5;
  int bx = rem % nx, by = rem / nx;
  int tx = threadIdx.x & 31, ty = threadIdx.x >> 5;
  int n0 = bx * 32, k0 = by * 32;
#pragma unroll
  for (int i = 0; i < 4; ++i)
    ts[ty + i * 8][tx] = in[(size_t)(k0 + ty + i * 8) * N + n0 + tx];
  __syncthreads();
#pragma unroll
  for (int i = 0; i < 4; ++i)
    out[(size_t)(n0 + ty + i * 8) * K + k0 + tx] = f2bf(ts[tx][ty + i * 8]);
}

// ------- bt-GEMM tile body (BK=32, double-buffered, 1 barrier / K-step) -------------
// A_F32 / B_F32: that operand is fp32 in global; reg-stage with fused cvt to bf16.
template <bool OUT_F32, bool A_F32, bool B_F32>
static __device__ __forceinline__ void gemm_bt_tile(
    const void* __restrict__ A, const void* __restrict__ Bt,
    const float* __restrict__ bias, bool rowBias, void* __restrict__ C,
    int N, int K, float scale, int bx, int by,
    unsigned short* As, unsigned short* Bs) {
  const int tid = threadIdx.x;
  const int w = tid >> 6;
  const int lhi = (tid >> 4) & 3;
  const int llo = tid & 15;
  const int wr = w >> 1, wc = w & 1;
  const size_t brow = (size_t)by * 128, bcol = (size_t)bx * 128;

  auto stage = [&](int k0, int bufi) {
#pragma unroll
    for (int i = 0; i < 2; ++i) {
      int o = i * 256 + tid;
      if constexpr (A_F32) {
        int row = o >> 2, gcol = o & 3;
        const float4* src = reinterpret_cast<const float4*>(
            (const float*)A + (brow + row) * (size_t)K + k0 + gcol * 8);
        float4 v0 = src[0], v1 = src[1];
        uint4 pk = {cvt_pk_bf16(v0.x, v0.y), cvt_pk_bf16(v0.z, v0.w),
                    cvt_pk_bf16(v1.x, v1.y), cvt_pk_bf16(v1.z, v1.w)};
        *reinterpret_cast<uint4*>(As + bufi * 4096 + (size_t)o * 8) = pk;
      } else {
        gld16((const unsigned short*)A + (brow + (o >> 2)) * (size_t)K + k0 + (o & 3) * 8,
              As + bufi * 4096 + (size_t)(i * 256 + w * 64) * 8);
      }
      if constexpr (B_F32) {
        int row = o >> 2, gcol = o & 3;
        const float4* src = reinterpret_cast<const float4*>(
            (const float*)Bt + (bcol + row) * (size_t)K + k0 + gcol * 8);
        float4 v0 = src[0], v1 = src[1];
        uint4 pk = {cvt_pk_bf16(v0.x, v0.y), cvt_pk_bf16(v0.z, v0.w),
                    cvt_pk_bf16(v1.x, v1.y), cvt_pk_bf16(v1.z, v1.w)};
        *reinterpret_cast<uint4*>(Bs + bufi * 4096 + (size_t)o * 8) = pk;
      } else {
        gld16((const unsigned short*)Bt + (bcol + (o >> 2)) * (size_t)K + k0 + (o & 3) * 8,
              Bs + bufi * 4096 + (size_t)(i * 256 + w * 64) * 8);
      }
    }
  };

  floatx4 acc[4][4];
#pragma unroll
  for (int i = 0; i < 4; ++i)
#pragma unroll
    for (int j = 0; j < 4; ++j)
      acc[i][j] = (floatx4){0.f, 0.f, 0.f, 0.f};

  stage(0, 0);
  __syncthreads();
  int buf = 0;
  const int nk = K >> 5;
  for (int t = 0; t < nk; ++t) {
    if (t + 1 < nk) stage((t + 1) * 32, buf ^ 1);
    const unsigned short* Ab = As + buf * 4096;
    const unsigned short* Bb = Bs + buf * 4096;
    short8 a[4], b[4];
#pragma unroll
    for (int f = 0; f < 4; ++f) {
      a[f] = *reinterpret_cast<const short8*>(Ab + (wr * 64 + f * 16 + llo) * 32 + lhi * 8);
      b[f] = *reinterpret_cast<const short8*>(Bb + (wc * 64 + f * 16 + llo) * 32 + lhi * 8);
    }
    __builtin_amdgcn_s_setprio(1);
#pragma unroll
    for (int i = 0; i < 4; ++i)
#pragma unroll
      for (int j = 0; j < 4; ++j)
        acc[i][j] = __builtin_amdgcn_mfma_f32_16x16x32_bf16(a[i], b[j], acc[i][j], 0, 0, 0);
    __builtin_amdgcn_s_setprio(0);
    __syncthreads();
    buf ^= 1;
  }

#pragma unroll
  for (int i = 0; i < 4; ++i) {
#pragma unroll
    for (int j = 0; j < 4; ++j) {
      size_t gr0 = brow + wr * 64 + i * 16 + lhi * 4;
      size_t gc = bcol + wc * 64 + j * 16 + llo;
#pragma unroll
      for (int r = 0; r < 4; ++r) {
        size_t grow = gr0 + r;
        float v = acc[i][j][r];
        v += rowBias ? bias[grow] : bias[gc];
        v *= scale;
        if (OUT_F32)
          ((float*)C)[grow * N + gc] = v;
        else
          ((unsigned short*)C)[grow * N + gc] = f2bf(v);
      }
    }
  }
}

// fused Q + K + V projections; fp32 activations converted in-staging.
// Q-seg: 2D XCD map — each XCD owns a (8-row x 8-col) tile quadrant: working set
// = 8MB activations + 4MB weights; rows walk fastest (weight panel hot in L2).
// K/V segs: round-11 column-major maps (proven).
__global__ __launch_bounds__(256) void k_gemm_qkv(
    const float* __restrict__ query, const unsigned short* __restrict__ WqT,
    const float* __restrict__ bq, unsigned short* __restrict__ qb,
    const float* __restrict__ key_in, const unsigned short* __restrict__ WkT,
    const float* __restrict__ bk, unsigned short* __restrict__ kb,
    const unsigned short* __restrict__ WvT, const float* __restrict__ value,
    const float* __restrict__ bv, unsigned short* __restrict__ vtb) {
  __shared__ __align__(16) unsigned short As[2 * 128 * 32];
  __shared__ __align__(16) unsigned short Bs[2 * 128 * 32];
  int bid = blockIdx.x;
  if (bid < 512) {
    int xcd = bid & 7, u = bid >> 3;            // u in [0,64)
    int by = (xcd >> 1) * 8 + (u & 7);          // 4 row-groups; rows walk fastest
    int bx = (xcd & 1) * 8 + (u >> 3);          // 2 col-groups
    gemm_bt_tile<false, true, false>(query, WqT, bq, false, qb, E_, E_,
                                     QK_SCALE * LOG2E_, bx, by, As, Bs);
  } else if (bid < 640) {
    int u = bid - 512;
    int cm = (u & 7) * 16 + (u >> 3);
    gemm_bt_tile<false, true, false>(key_in, WkT, bk, false, kb, KV_, E_, 1.0f,
                                     cm >> 5, cm & 31, As, Bs);
  } else {
    int u = bid - 640;
    int cm = (u & 7) * 16 + (u >> 3);
    gemm_bt_tile<false, false, true>(WvT, value, bv, true, vtb, BS_, E_, 1.0f,
                                     cm >> 2, cm & 3, As, Bs);
  }
}

__global__ __launch_bounds__(256) void k_gemm_o(
    const unsigned short* __restrict__ A, const unsigned short* __restrict__ Bt,
    const float* __restrict__ bias, float* __restrict__ C) {
  __shared__ __align__(16) unsigned short As[2 * 128 * 32];
  __shared__ __align__(16) unsigned short Bs[2 * 128 * 32];
  int xcd = blockIdx.x & 7, u = blockIdx.x >> 3;
  int by = (xcd >> 1) * 8 + (u & 7);
  int bx = (xcd & 1) * 8 + (u >> 3);
  gemm_bt_tile<true, false, false>(A, Bt, bias, false, C, E_, E_, 1.0f,
                                   bx, by, As, Bs);
}

// ---------------- fused GQA flash attention (QBLK=256, 8 waves, K+V dbuf in LDS) -----
// XCD-affinity swizzle: bid%8 selects (b,g) so each XCD's L2 owns ONE KV working set.
__global__ __launch_bounds__(512) void k_attn(
    const unsigned short* __restrict__ qb, const unsigned short* __restrict__ kb,
    const unsigned short* __restrict__ vt, unsigned short* __restrict__ attn) {
  __shared__ __align__(16) unsigned short Ks[2][64 * 128];
  __shared__ __align__(16) unsigned short Vs[2][128 * 64];
  __shared__ __align__(16) unsigned short Ps[8][32 * 64];

  const int tid = threadIdx.x;
  const int w = tid >> 6;
  const int lhi = (tid >> 4) & 3;
  const int llo = tid & 15;
  const int bid = blockIdx.x;
  const int xcd = bid & 7;
  const int b = xcd >> 2, g = xcd & 3;
  const int inner = bid >> 3;
  const int hq = inner & 3, qt = inner >> 2;
  const int h = g * 4 + hq;

  char* PsW = (char*)&Ps[0][0] + w * 4096;

  short8 qf[2][4];
#pragma unroll
  for (int rt = 0; rt < 2; ++rt)
#pragma unroll
    for (int hc = 0; hc < 4; ++hc) {
      int row = qt * 256 + w * 32 + rt * 16 + llo;
      qf[rt][hc] = *reinterpret_cast<const short8*>(
          qb + ((size_t)(b * 2048 + row)) * 2048 + h * 128 + hc * 32 + lhi * 8);
    }

  floatx4 acc[2][8];
#pragma unroll
  for (int rt = 0; rt < 2; ++rt)
#pragma unroll
    for (int dc = 0; dc < 8; ++dc)
      acc[rt][dc] = (floatx4){0.f, 0.f, 0.f, 0.f};
  float m_[2] = {-1e30f, -1e30f};
  float l_[2] = {0.f, 0.f};

  auto stage = [&](int kv0, int buf) {
#pragma unroll
    for (int i = 0; i < 2; ++i) {
      int o = i * 512 + tid;
      int row = o >> 4, gr2 = (o & 15) ^ (row & 7);
      gld16(kb + ((size_t)(b * 2048 + kv0 + row)) * 512 + g * 128 + gr2 * 8,
            &Ks[buf][(size_t)(i * 512 + w * 64) * 8]);
    }
#pragma unroll
    for (int i = 0; i < 2; ++i) {
      int o = i * 512 + tid;
      int row = o >> 3, gr2 = (o & 7) ^ (row & 7);
      gld16(vt + ((size_t)(g * 128 + row)) * 4096 + b * 2048 + kv0 + gr2 * 8,
            &Vs[buf][(size_t)(i * 512 + w * 64) * 8]);
    }
  };

  stage(0, 0);
  __syncthreads();
  int buf = 0;

  for (int t = 0; t < 32; ++t) {
    const int kv0 = t * 64;
    if (t < 31) stage(kv0 + 64, buf ^ 1);

    floatx4 sc[2][4];
#pragma unroll
    for (int rt = 0; rt < 2; ++rt)
#pragma unroll
      for (int c = 0; c < 4; ++c)
        sc[rt][c] = (floatx4){0.f, 0.f, 0.f, 0.f};
    __builtin_amdgcn_s_setprio(1);
#pragma unroll
    for (int c = 0; c < 4; ++c) {
      int krow = c * 16 + llo;
#pragma unroll
      for (int hc = 0; hc < 4; ++hc) {
        int byteoff = krow * 256 + ((hc * 64 + lhi * 16) ^ ((krow & 7) << 4));
        short8 kf = *reinterpret_cast<const short8*>((const char*)&Ks[buf][0] + byteoff);
        sc[0][c] = __builtin_amdgcn_mfma_f32_16x16x32_bf16(kf, qf[0][hc], sc[0][c], 0, 0, 0);
        sc[1][c] = __builtin_amdgcn_mfma_f32_16x16x32_bf16(kf, qf[1][hc], sc[1][c], 0, 0, 0);
      }
    }
    __builtin_amdgcn_s_setprio(0);

#pragma unroll
    for (int rt = 0; rt < 2; ++rt) {
      float pm = sc[rt][0][0];
#pragma unroll
      for (int c = 0; c < 4; ++c)
#pragma unroll
        for (int r = 0; r < 4; ++r) pm = fmaxf(pm, sc[rt][c][r]);
      if (__any(pm > m_[rt] + 8.0f)) {
        float t2 = pm;
        t2 = fmaxf(t2, __shfl_xor(t2, 16));
        t2 = fmaxf(t2, __shfl_xor(t2, 32));
        float m2 = fmaxf(m_[rt], t2);
        float scr = __builtin_amdgcn_exp2f(m_[rt] - m2);
        m_[rt] = m2;
        l_[rt] *= scr;
#pragma unroll
        for (int r = 0; r < 4; ++r) {
          float s_r = __shfl(scr, (tid & 48) | (((tid >> 2) & 12) + r));
#pragma unroll
          for (int dc = 0; dc < 8; ++dc) acc[rt][dc][r] *= s_r;
        }
      }
      float lsum = l_[rt];
#pragma unroll
      for (int c = 0; c < 4; ++c) {
        float e0 = __builtin_amdgcn_exp2f(sc[rt][c][0] - m_[rt]);
        float e1 = __builtin_amdgcn_exp2f(sc[rt][c][1] - m_[rt]);
        float e2 = __builtin_amdgcn_exp2f(sc[rt][c][2] - m_[rt]);
        float e3 = __builtin_amdgcn_exp2f(sc[rt][c][3] - m_[rt]);
        lsum += (e0 + e1) + (e2 + e3);
        uint2 pk;
        pk.x = cvt_pk_bf16(e0, e1);
        pk.y = cvt_pk_bf16(e2, e3);
        int byteoff = (rt * 16 + llo) * 128 + ((c * 32 + lhi * 8) ^ ((llo & 7) << 4));
        *reinterpret_cast<uint2*>(PsW + byteoff) = pk;
      }
      l_[rt] = lsum;
    }

    short8 pf[2][2];
#pragma unroll
    for (int rt = 0; rt < 2; ++rt)
#pragma unroll
      for (int kc = 0; kc < 2; ++kc) {
        int byteoff = (rt * 16 + llo) * 128 + ((kc * 64 + lhi * 16) ^ ((llo & 7) << 4));
        pf[rt][kc] = *reinterpret_cast<const short8*>(PsW + byteoff);
      }
    __builtin_amdgcn_s_setprio(1);
#pragma unroll
    for (int dc = 0; dc < 8; ++dc) {
      int vrow = dc * 16 + llo;
      int bo0 = vrow * 128 + ((lhi * 16) ^ ((vrow & 7) << 4));
      int bo1 = vrow * 128 + ((64 + lhi * 16) ^ ((vrow & 7) << 4));
      short8 vf0 = *reinterpret_cast<const short8*>((const char*)&Vs[buf][0] + bo0);
      short8 vf1 = *reinterpret_cast<const short8*>((const char*)&Vs[buf][0] + bo1);
      acc[0][dc] = __builtin_amdgcn_mfma_f32_16x16x32_bf16(pf[0][0], vf0, acc[0][dc], 0, 0, 0);
      acc[1][dc] = __builtin_amdgcn_mfma_f32_16x16x32_bf16(pf[1][0], vf0, acc[1][dc], 0, 0, 0);
      acc[0][dc] = __builtin_amdgcn_mfma_f32_16x16x32_bf16(pf[0][1], vf1, acc[0][dc], 0, 0, 0);
      acc[1][dc] = __builtin_amdgcn_mfma_f32_16x16x32_bf16(pf[1][1], vf1, acc[1][dc], 0, 0, 0);
    }
    __builtin_amdgcn_s_setprio(0);
    __syncthreads();
    buf ^= 1;
  }

#pragma unroll
  for (int rt = 0; rt < 2; ++rt) {
    float t2 = l_[rt];
    t2 += __shfl_xor(t2, 16);
    t2 += __shfl_xor(t2, 32);
    float linv = 1.0f / t2;
    float lr[4];
#pragma unroll
    for (int r = 0; r < 4; ++r)
      lr[r] = __shfl(linv, (tid & 48) | (((tid >> 2) & 12) + r));
#pragma unroll
    for (int dc = 0; dc < 8; ++dc)
#pragma unroll
      for (int r = 0; r < 4; ++r) {
        int row = qt * 256 + w * 32 + rt * 16 + lhi * 4 + r;
        float v = acc[rt][dc][r] * lr[r];
        attn[((size_t)(b * 2048 + row)) * 2048 + h * 128 + dc * 16 + llo] = f2bf(v);
      }
  }
}

extern "C" void kernel_launch(void* const* d_in, const int* in_sizes, int n_in,
                              void* d_out, int out_size, void* d_ws, size_t ws_size,
                              hipStream_t stream) {
  const float* query  = (const float*)d_in[0];
  const float* key_in = (const float*)d_in[1];
  const float* value  = (const float*)d_in[2];
  const float* Wq = (const float*)d_in[3];
  const float* bq = (const float*)d_in[4];
  const float* Wk = (const float*)d_in[5];
  const float* bk = (const float*)d_in[6];
  const float* Wv = (const float*)d_in[7];
  const float* bv = (const float*)d_in[8];
  const float* Wo = (const float*)d_in[9];
  const float* bo = (const float*)d_in[10];
  float* out = (float*)d_out;

  char* ws = (char*)d_ws;
  size_t off = 0;
  auto alloc = [&](size_t bytes) {
    char* p = ws + off;
    off += (bytes + 255) & ~(size_t)255;
    return p;
  };
  unsigned short* WqT  = (unsigned short*)alloc((size_t)E_ * E_ * 2);
  unsigned short* WkT  = (unsigned short*)alloc((size_t)KV_ * E_ * 2);
  unsigned short* WvT  = (unsigned short*)alloc((size_t)KV_ * E_ * 2);
  unsigned short* WoT  = (unsigned short*)alloc((size_t)E_ * E_ * 2);
  unsigned short* qb   = (unsigned short*)alloc((size_t)BS_ * E_ * 2);
  unsigned short* kb   = (unsigned short*)alloc((size_t)BS_ * KV_ * 2);
  unsigned short* vtb  = (unsigned short*)alloc((size_t)KV_ * BS_ * 2);
  unsigned short* attb = (unsigned short*)alloc((size_t)BS_ * E_ * 2);

  k_prep<<<10240, 256, 0, stream>>>(Wq, WqT, Wk, WkT, Wv, WvT, Wo, WoT);
  k_gemm_qkv<<<768, 256, 0, stream>>>(query, WqT, bq, qb, key_in, WkT, bk, kb,
                                      WvT, value, bv, vtb);
  k_attn<<<B_ * NH_ * (S_ / 256), 512, 0, stream>>>(qb, kb, vtb, attb);
  k_gemm_o<<<512, 256, 0, stream>>>(attb, WoT, bo, out);
}

// Round 15
// 228.588 us; speedup vs baseline: 1.1595x; 1.0183x over previous
//
#include <hip/hip_runtime.h>
#include <hip/hip_bf16.h>

#define E_ 2048
#define S_ 2048
#define B_ 2
#define BS_ 4096
#define KV_ 512
#define NH_ 16
#define G_ 4
#define HD_ 128
#define QK_SCALE 0.08838834764831845f
#define LOG2E_ 1.4426950408889634f

typedef __attribute__((ext_vector_type(8))) short short8;
typedef __attribute__((ext_vector_type(4))) float floatx4;
typedef __attribute__((ext_vector_type(4))) unsigned short ushort4_;

static __device__ __forceinline__ unsigned short f2bf(float f) {
  unsigned int u = __builtin_bit_cast(unsigned int, f);
  u += 0x7fffu + ((u >> 16) & 1u);
  return (unsigned short)(u >> 16);
}

static __device__ __forceinline__ unsigned int cvt_pk_bf16(float lo, float hi) {
  unsigned int r;
  asm("v_cvt_pk_bf16_f32 %0, %1, %2" : "=v"(r) : "v"(lo), "v"(hi));
  return r;
}

static __device__ __forceinline__ void gld16(const void* g, void* l) {
  __builtin_amdgcn_global_load_lds(
      (const __attribute__((address_space(1))) unsigned int*)g,
      (__attribute__((address_space(3))) unsigned int*)l, 16, 0, 0);
}

// ---------------- prep: 4 weight transposes (fp32 [K][N] -> bf16 [N][K]) -------------
__global__ __launch_bounds__(256) void k_prep(
    const float* __restrict__ Wq, unsigned short* __restrict__ WqT,
    const float* __restrict__ Wk, unsigned short* __restrict__ WkT,
    const float* __restrict__ Wv, unsigned short* __restrict__ WvT,
    const float* __restrict__ Wo, unsigned short* __restrict__ WoT) {
  __shared__ float ts[32][33];
  int t = blockIdx.x;
  const float* in; unsigned short* out; int N; int rem;
  if (t < 4096)      { in = Wq; out = WqT; N = 2048; rem = t; }
  else if (t < 5120) { in = Wk; out = WkT; N = 512;  rem = t - 4096; }
  else if (t < 6144) { in = Wv; out = WvT; N = 512;  rem = t - 5120; }
  else               { in = Wo; out = WoT; N = 2048; rem = t - 6144; }
  const int K = 2048;
  int nx = N >> 5;
  int bx = rem % nx, by = rem / nx;
  int tx = threadIdx.x & 31, ty = threadIdx.x >> 5;
  int n0 = bx * 32, k0 = by * 32;
#pragma unroll
  for (int i = 0; i < 4; ++i)
    ts[ty + i * 8][tx] = in[(size_t)(k0 + ty + i * 8) * N + n0 + tx];
  __syncthreads();
#pragma unroll
  for (int i = 0; i < 4; ++i)
    out[(size_t)(n0 + ty + i * 8) * K + k0 + tx] = f2bf(ts[tx][ty + i * 8]);
}

// ------- bt-GEMM tile body (BK=32, double-buffered, 1 barrier / K-step) -------------
// A_F32 / B_F32: that operand is fp32 in global; staged RAW via global_load_lds with
// XOR-swizzled SOURCE granules (linear LDS dest), converted to bf16 in the fragment
// read (2x ds_read_b128 fp32 + 4x v_cvt_pk_bf16_f32). fp32 buffer = 2 x 8192 shorts.
template <bool OUT_F32, bool A_F32, bool B_F32>
static __device__ __forceinline__ void gemm_bt_tile(
    const void* __restrict__ A, const void* __restrict__ Bt,
    const float* __restrict__ bias, bool rowBias, void* __restrict__ C,
    int N, int K, float scale, int bx, int by,
    unsigned short* As, unsigned short* Bs) {
  const int tid = threadIdx.x;
  const int w = tid >> 6;
  const int lhi = (tid >> 4) & 3;
  const int llo = tid & 15;
  const int wr = w >> 1, wc = w & 1;
  const size_t brow = (size_t)by * 128, bcol = (size_t)bx * 128;
  constexpr int ASTR = A_F32 ? 8192 : 4096;   // shorts per buffer
  constexpr int BSTR = B_F32 ? 8192 : 4096;

  auto stage = [&](int k0, int bufi) {
    if constexpr (A_F32) {
#pragma unroll
      for (int i = 0; i < 4; ++i) {
        int o = i * 256 + tid;
        int row = o >> 3, gs = (o & 7) ^ (row & 7);
        gld16((const float*)A + (brow + row) * (size_t)K + k0 + gs * 4,
              As + bufi * ASTR + (size_t)(i * 256 + w * 64) * 8);
      }
    } else {
#pragma unroll
      for (int i = 0; i < 2; ++i) {
        int o = i * 256 + tid;
        gld16((const unsigned short*)A + (brow + (o >> 2)) * (size_t)K + k0 + (o & 3) * 8,
              As + bufi * ASTR + (size_t)(i * 256 + w * 64) * 8);
      }
    }
    if constexpr (B_F32) {
#pragma unroll
      for (int i = 0; i < 4; ++i) {
        int o = i * 256 + tid;
        int row = o >> 3, gs = (o & 7) ^ (row & 7);
        gld16((const float*)Bt + (bcol + row) * (size_t)K + k0 + gs * 4,
              Bs + bufi * BSTR + (size_t)(i * 256 + w * 64) * 8);
      }
    } else {
#pragma unroll
      for (int i = 0; i < 2; ++i) {
        int o = i * 256 + tid;
        gld16((const unsigned short*)Bt + (bcol + (o >> 2)) * (size_t)K + k0 + (o & 3) * 8,
              Bs + bufi * BSTR + (size_t)(i * 256 + w * 64) * 8);
      }
    }
  };

  // fragment fetch: fp32-staged operand converts in-register
  auto frag_f32 = [&](const unsigned short* buf, int row) -> short8 {
    const char* p = (const char*)buf;
    int g0 = (lhi * 2) ^ (row & 7);
    float4 v0 = *reinterpret_cast<const float4*>(p + row * 128 + g0 * 16);
    float4 v1 = *reinterpret_cast<const float4*>(p + row * 128 + (g0 ^ 1) * 16);
    uint4 pk = {cvt_pk_bf16(v0.x, v0.y), cvt_pk_bf16(v0.z, v0.w),
                cvt_pk_bf16(v1.x, v1.y), cvt_pk_bf16(v1.z, v1.w)};
    return __builtin_bit_cast(short8, pk);
  };

  floatx4 acc[4][4];
#pragma unroll
  for (int i = 0; i < 4; ++i)
#pragma unroll
    for (int j = 0; j < 4; ++j)
      acc[i][j] = (floatx4){0.f, 0.f, 0.f, 0.f};

  stage(0, 0);
  __syncthreads();
  int buf = 0;
  const int nk = K >> 5;
  for (int t = 0; t < nk; ++t) {
    if (t + 1 < nk) stage((t + 1) * 32, buf ^ 1);
    const unsigned short* Ab = As + buf * ASTR;
    const unsigned short* Bb = Bs + buf * BSTR;
    short8 a[4], b[4];
#pragma unroll
    for (int f = 0; f < 4; ++f) {
      int ra = wr * 64 + f * 16 + llo;
      int rb = wc * 64 + f * 16 + llo;
      if constexpr (A_F32)
        a[f] = frag_f32(Ab, ra);
      else
        a[f] = *reinterpret_cast<const short8*>(Ab + ra * 32 + lhi * 8);
      if constexpr (B_F32)
        b[f] = frag_f32(Bb, rb);
      else
        b[f] = *reinterpret_cast<const short8*>(Bb + rb * 32 + lhi * 8);
    }
    __builtin_amdgcn_s_setprio(1);
#pragma unroll
    for (int i = 0; i < 4; ++i)
#pragma unroll
      for (int j = 0; j < 4; ++j)
        acc[i][j] = __builtin_amdgcn_mfma_f32_16x16x32_bf16(a[i], b[j], acc[i][j], 0, 0, 0);
    __builtin_amdgcn_s_setprio(0);
    __syncthreads();
    buf ^= 1;
  }

#pragma unroll
  for (int i = 0; i < 4; ++i) {
#pragma unroll
    for (int j = 0; j < 4; ++j) {
      size_t gr0 = brow + wr * 64 + i * 16 + lhi * 4;
      size_t gc = bcol + wc * 64 + j * 16 + llo;
#pragma unroll
      for (int r = 0; r < 4; ++r) {
        size_t grow = gr0 + r;
        float v = acc[i][j][r];
        v += rowBias ? bias[grow] : bias[gc];
        v *= scale;
        if (OUT_F32)
          ((float*)C)[grow * N + gc] = v;
        else
          ((unsigned short*)C)[grow * N + gc] = f2bf(v);
      }
    }
  }
}

// fused Q + K + V projections; fp32 activations staged raw via global_load_lds.
// Q-seg: 2D XCD map (proven fetch reduction r14). K/V segs: r11 col-major maps.
// LDS: 48 KB partitioned per segment (fp32 operand 32 KB + bf16 operand 16 KB).
__global__ __launch_bounds__(256) void k_gemm_qkv(
    const float* __restrict__ query, const unsigned short* __restrict__ WqT,
    const float* __restrict__ bq, unsigned short* __restrict__ qb,
    const float* __restrict__ key_in, const unsigned short* __restrict__ WkT,
    const float* __restrict__ bk, unsigned short* __restrict__ kb,
    const unsigned short* __restrict__ WvT, const float* __restrict__ value,
    const float* __restrict__ bv, unsigned short* __restrict__ vtb) {
  __shared__ __align__(16) unsigned short lds[24576];   // 48 KB
  int bid = blockIdx.x;
  if (bid < 512) {
    int xcd = bid & 7, u = bid >> 3;
    int by = (xcd >> 1) * 8 + (u & 7);
    int bx = (xcd & 1) * 8 + (u >> 3);
    gemm_bt_tile<false, true, false>(query, WqT, bq, false, qb, E_, E_,
                                     QK_SCALE * LOG2E_, bx, by,
                                     lds, lds + 16384);
  } else if (bid < 640) {
    int u = bid - 512;
    int cm = (u & 7) * 16 + (u >> 3);
    gemm_bt_tile<false, true, false>(key_in, WkT, bk, false, kb, KV_, E_, 1.0f,
                                     cm >> 5, cm & 31, lds, lds + 16384);
  } else {
    int u = bid - 640;
    int cm = (u & 7) * 16 + (u >> 3);
    gemm_bt_tile<false, false, true>(WvT, value, bv, true, vtb, BS_, E_, 1.0f,
                                     cm >> 2, cm & 3, lds, lds + 8192);
  }
}

__global__ __launch_bounds__(256) void k_gemm_o(
    const unsigned short* __restrict__ A, const unsigned short* __restrict__ Bt,
    const float* __restrict__ bias, float* __restrict__ C) {
  __shared__ __align__(16) unsigned short As[2 * 128 * 32];
  __shared__ __align__(16) unsigned short Bs[2 * 128 * 32];
  int cm = (blockIdx.x & 7) * 64 + (blockIdx.x >> 3);
  gemm_bt_tile<true, false, false>(A, Bt, bias, false, C, E_, E_, 1.0f,
                                   cm >> 5, cm & 31, As, Bs);
}

// ---------------- fused GQA flash attention (QBLK=256, 8 waves, K+V dbuf in LDS) -----
// XCD-affinity swizzle: bid%8 selects (b,g) so each XCD's L2 owns ONE KV working set.
__global__ __launch_bounds__(512) void k_attn(
    const unsigned short* __restrict__ qb, const unsigned short* __restrict__ kb,
    const unsigned short* __restrict__ vt, unsigned short* __restrict__ attn) {
  __shared__ __align__(16) unsigned short Ks[2][64 * 128];
  __shared__ __align__(16) unsigned short Vs[2][128 * 64];
  __shared__ __align__(16) unsigned short Ps[8][32 * 64];

  const int tid = threadIdx.x;
  const int w = tid >> 6;
  const int lhi = (tid >> 4) & 3;
  const int llo = tid & 15;
  const int bid = blockIdx.x;
  const int xcd = bid & 7;
  const int b = xcd >> 2, g = xcd & 3;
  const int inner = bid >> 3;
  const int hq = inner & 3, qt = inner >> 2;
  const int h = g * 4 + hq;

  char* PsW = (char*)&Ps[0][0] + w * 4096;

  short8 qf[2][4];
#pragma unroll
  for (int rt = 0; rt < 2; ++rt)
#pragma unroll
    for (int hc = 0; hc < 4; ++hc) {
      int row = qt * 256 + w * 32 + rt * 16 + llo;
      qf[rt][hc] = *reinterpret_cast<const short8*>(
          qb + ((size_t)(b * 2048 + row)) * 2048 + h * 128 + hc * 32 + lhi * 8);
    }

  floatx4 acc[2][8];
#pragma unroll
  for (int rt = 0; rt < 2; ++rt)
#pragma unroll
    for (int dc = 0; dc < 8; ++dc)
      acc[rt][dc] = (floatx4){0.f, 0.f, 0.f, 0.f};
  float m_[2] = {-1e30f, -1e30f};
  float l_[2] = {0.f, 0.f};

  auto stage = [&](int kv0, int buf) {
#pragma unroll
    for (int i = 0; i < 2; ++i) {
      int o = i * 512 + tid;
      int row = o >> 4, gr2 = (o & 15) ^ (row & 7);
      gld16(kb + ((size_t)(b * 2048 + kv0 + row)) * 512 + g * 128 + gr2 * 8,
            &Ks[buf][(size_t)(i * 512 + w * 64) * 8]);
    }
#pragma unroll
    for (int i = 0; i < 2; ++i) {
      int o = i * 512 + tid;
      int row = o >> 3, gr2 = (o & 7) ^ (row & 7);
      gld16(vt + ((size_t)(g * 128 + row)) * 4096 + b * 2048 + kv0 + gr2 * 8,
            &Vs[buf][(size_t)(i * 512 + w * 64) * 8]);
    }
  };

  stage(0, 0);
  __syncthreads();
  int buf = 0;

  for (int t = 0; t < 32; ++t) {
    const int kv0 = t * 64;
    if (t < 31) stage(kv0 + 64, buf ^ 1);

    floatx4 sc[2][4];
#pragma unroll
    for (int rt = 0; rt < 2; ++rt)
#pragma unroll
      for (int c = 0; c < 4; ++c)
        sc[rt][c] = (floatx4){0.f, 0.f, 0.f, 0.f};
    __builtin_amdgcn_s_setprio(1);
#pragma unroll
    for (int c = 0; c < 4; ++c) {
      int krow = c * 16 + llo;
#pragma unroll
      for (int hc = 0; hc < 4; ++hc) {
        int byteoff = krow * 256 + ((hc * 64 + lhi * 16) ^ ((krow & 7) << 4));
        short8 kf = *reinterpret_cast<const short8*>((const char*)&Ks[buf][0] + byteoff);
        sc[0][c] = __builtin_amdgcn_mfma_f32_16x16x32_bf16(kf, qf[0][hc], sc[0][c], 0, 0, 0);
        sc[1][c] = __builtin_amdgcn_mfma_f32_16x16x32_bf16(kf, qf[1][hc], sc[1][c], 0, 0, 0);
      }
    }
    __builtin_amdgcn_s_setprio(0);

#pragma unroll
    for (int rt = 0; rt < 2; ++rt) {
      float pm = sc[rt][0][0];
#pragma unroll
      for (int c = 0; c < 4; ++c)
#pragma unroll
        for (int r = 0; r < 4; ++r) pm = fmaxf(pm, sc[rt][c][r]);
      if (__any(pm > m_[rt] + 8.0f)) {
        float t2 = pm;
        t2 = fmaxf(t2, __shfl_xor(t2, 16));
        t2 = fmaxf(t2, __shfl_xor(t2, 32));
        float m2 = fmaxf(m_[rt], t2);
        float scr = __builtin_amdgcn_exp2f(m_[rt] - m2);
        m_[rt] = m2;
        l_[rt] *= scr;
#pragma unroll
        for (int r = 0; r < 4; ++r) {
          float s_r = __shfl(scr, (tid & 48) | (((tid >> 2) & 12) + r));
#pragma unroll
          for (int dc = 0; dc < 8; ++dc) acc[rt][dc][r] *= s_r;
        }
      }
      float lsum = l_[rt];
#pragma unroll
      for (int c = 0; c < 4; ++c) {
        float e0 = __builtin_amdgcn_exp2f(sc[rt][c][0] - m_[rt]);
        float e1 = __builtin_amdgcn_exp2f(sc[rt][c][1] - m_[rt]);
        float e2 = __builtin_amdgcn_exp2f(sc[rt][c][2] - m_[rt]);
        float e3 = __builtin_amdgcn_exp2f(sc[rt][c][3] - m_[rt]);
        lsum += (e0 + e1) + (e2 + e3);
        uint2 pk;
        pk.x = cvt_pk_bf16(e0, e1);
        pk.y = cvt_pk_bf16(e2, e3);
        int byteoff = (rt * 16 + llo) * 128 + ((c * 32 + lhi * 8) ^ ((llo & 7) << 4));
        *reinterpret_cast<uint2*>(PsW + byteoff) = pk;
      }
      l_[rt] = lsum;
    }

    short8 pf[2][2];
#pragma unroll
    for (int rt = 0; rt < 2; ++rt)
#pragma unroll
      for (int kc = 0; kc < 2; ++kc) {
        int byteoff = (rt * 16 + llo) * 128 + ((kc * 64 + lhi * 16) ^ ((llo & 7) << 4));
        pf[rt][kc] = *reinterpret_cast<const short8*>(PsW + byteoff);
      }
    __builtin_amdgcn_s_setprio(1);
#pragma unroll
    for (int dc = 0; dc < 8; ++dc) {
      int vrow = dc * 16 + llo;
      int bo0 = vrow * 128 + ((lhi * 16) ^ ((vrow & 7) << 4));
      int bo1 = vrow * 128 + ((64 + lhi * 16) ^ ((vrow & 7) << 4));
      short8 vf0 = *reinterpret_cast<const short8*>((const char*)&Vs[buf][0] + bo0);
      short8 vf1 = *reinterpret_cast<const short8*>((const char*)&Vs[buf][0] + bo1);
      acc[0][dc] = __builtin_amdgcn_mfma_f32_16x16x32_bf16(pf[0][0], vf0, acc[0][dc], 0, 0, 0);
      acc[1][dc] = __builtin_amdgcn_mfma_f32_16x16x32_bf16(pf[1][0], vf0, acc[1][dc], 0, 0, 0);
      acc[0][dc] = __builtin_amdgcn_mfma_f32_16x16x32_bf16(pf[0][1], vf1, acc[0][dc], 0, 0, 0);
      acc[1][dc] = __builtin_amdgcn_mfma_f32_16x16x32_bf16(pf[1][1], vf1, acc[1][dc], 0, 0, 0);
    }
    __builtin_amdgcn_s_setprio(0);
    __syncthreads();
    buf ^= 1;
  }

#pragma unroll
  for (int rt = 0; rt < 2; ++rt) {
    float t2 = l_[rt];
    t2 += __shfl_xor(t2, 16);
    t2 += __shfl_xor(t2, 32);
    float linv = 1.0f / t2;
    float lr[4];
#pragma unroll
    for (int r = 0; r < 4; ++r)
      lr[r] = __shfl(linv, (tid & 48) | (((tid >> 2) & 12) + r));
#pragma unroll
    for (int dc = 0; dc < 8; ++dc)
#pragma unroll
      for (int r = 0; r < 4; ++r) {
        int row = qt * 256 + w * 32 + rt * 16 + lhi * 4 + r;
        float v = acc[rt][dc][r] * lr[r];
        attn[((size_t)(b * 2048 + row)) * 2048 + h * 128 + dc * 16 + llo] = f2bf(v);
      }
  }
}

extern "C" void kernel_launch(void* const* d_in, const int* in_sizes, int n_in,
                              void* d_out, int out_size, void* d_ws, size_t ws_size,
                              hipStream_t stream) {
  const float* query  = (const float*)d_in[0];
  const float* key_in = (const float*)d_in[1];
  const float* value  = (const float*)d_in[2];
  const float* Wq = (const float*)d_in[3];
  const float* bq = (const float*)d_in[4];
  const float* Wk = (const float*)d_in[5];
  const float* bk = (const float*)d_in[6];
  const float* Wv = (const float*)d_in[7];
  const float* bv = (const float*)d_in[8];
  const float* Wo = (const float*)d_in[9];
  const float* bo = (const float*)d_in[10];
  float* out = (float*)d_out;

  char* ws = (char*)d_ws;
  size_t off = 0;
  auto alloc = [&](size_t bytes) {
    char* p = ws + off;
    off += (bytes + 255) & ~(size_t)255;
    return p;
  };
  unsigned short* WqT  = (unsigned short*)alloc((size_t)E_ * E_ * 2);
  unsigned short* WkT  = (unsigned short*)alloc((size_t)KV_ * E_ * 2);
  unsigned short* WvT  = (unsigned short*)alloc((size_t)KV_ * E_ * 2);
  unsigned short* WoT  = (unsigned short*)alloc((size_t)E_ * E_ * 2);
  unsigned short* qb   = (unsigned short*)alloc((size_t)BS_ * E_ * 2);
  unsigned short* kb   = (unsigned short*)alloc((size_t)BS_ * KV_ * 2);
  unsigned short* vtb  = (unsigned short*)alloc((size_t)KV_ * BS_ * 2);
  unsigned short* attb = (unsigned short*)alloc((size_t)BS_ * E_ * 2);

  k_prep<<<10240, 256, 0, stream>>>(Wq, WqT, Wk, WkT, Wv, WvT, Wo, WoT);
  k_gemm_qkv<<<768, 256, 0, stream>>>(query, WqT, bq, qb, key_in, WkT, bk, kb,
                                      WvT, value, bv, vtb);
  k_attn<<<B_ * NH_ * (S_ / 256), 512, 0, stream>>>(qb, kb, vtb, attb);
  k_gemm_o<<<512, 256, 0, stream>>>(attb, WoT, bo, out);
}

// Round 16
// 218.871 us; speedup vs baseline: 1.2110x; 1.0444x over previous
//
#include <hip/hip_runtime.h>
#include <hip/hip_bf16.h>

#define E_ 2048
#define S_ 2048
#define B_ 2
#define BS_ 4096
#define KV_ 512
#define NH_ 16
#define G_ 4
#define HD_ 128
#define QK_SCALE 0.08838834764831845f
#define LOG2E_ 1.4426950408889634f

typedef __attribute__((ext_vector_type(8))) short short8;
typedef __attribute__((ext_vector_type(4))) float floatx4;
typedef __attribute__((ext_vector_type(4))) unsigned short ushort4_;

static __device__ __forceinline__ unsigned short f2bf(float f) {
  unsigned int u = __builtin_bit_cast(unsigned int, f);
  u += 0x7fffu + ((u >> 16) & 1u);
  return (unsigned short)(u >> 16);
}

static __device__ __forceinline__ unsigned int cvt_pk_bf16(float lo, float hi) {
  unsigned int r;
  asm("v_cvt_pk_bf16_f32 %0, %1, %2" : "=v"(r) : "v"(lo), "v"(hi));
  return r;
}

static __device__ __forceinline__ void gld16(const void* g, void* l) {
  __builtin_amdgcn_global_load_lds(
      (const __attribute__((address_space(1))) unsigned int*)g,
      (__attribute__((address_space(3))) unsigned int*)l, 16, 0, 0);
}

// ---------------- prep: 4 weight transposes (fp32 [K][N] -> bf16 [N][K]) -------------
__global__ __launch_bounds__(256) void k_prep(
    const float* __restrict__ Wq, unsigned short* __restrict__ WqT,
    const float* __restrict__ Wk, unsigned short* __restrict__ WkT,
    const float* __restrict__ Wv, unsigned short* __restrict__ WvT,
    const float* __restrict__ Wo, unsigned short* __restrict__ WoT) {
  __shared__ float ts[32][33];
  int t = blockIdx.x;
  const float* in; unsigned short* out; int N; int rem;
  if (t < 4096)      { in = Wq; out = WqT; N = 2048; rem = t; }
  else if (t < 5120) { in = Wk; out = WkT; N = 512;  rem = t - 4096; }
  else if (t < 6144) { in = Wv; out = WvT; N = 512;  rem = t - 5120; }
  else               { in = Wo; out = WoT; N = 2048; rem = t - 6144; }
  const int K = 2048;
  int nx = N >> 5;
  int bx = rem % nx, by = rem / nx;
  int tx = threadIdx.x & 31, ty = threadIdx.x >> 5;
  int n0 = bx * 32, k0 = by * 32;
#pragma unroll
  for (int i = 0; i < 4; ++i)
    ts[ty + i * 8][tx] = in[(size_t)(k0 + ty + i * 8) * N + n0 + tx];
  __syncthreads();
#pragma unroll
  for (int i = 0; i < 4; ++i)
    out[(size_t)(n0 + ty + i * 8) * K + k0 + tx] = f2bf(ts[tx][ty + i * 8]);
}

// ------- bt-GEMM tile body (BK=32, double-buffered, 1 barrier / K-step) -------------
// A_F32 / B_F32: that operand is fp32 in global; staged RAW via global_load_lds
// (source-granule swizzle g^(row&7), conflict-free), converted to bf16 in the
// fragment read. bf16 operands: [128][32] tile staged with source-granule swizzle
// g^((row>>1)&3) and matching read XOR -> 2-way (free) instead of 8-way conflicts.
template <bool OUT_F32, bool A_F32, bool B_F32>
static __device__ __forceinline__ void gemm_bt_tile(
    const void* __restrict__ A, const void* __restrict__ Bt,
    const float* __restrict__ bias, bool rowBias, void* __restrict__ C,
    int N, int K, float scale, int bx, int by,
    unsigned short* As, unsigned short* Bs) {
  const int tid = threadIdx.x;
  const int w = tid >> 6;
  const int lhi = (tid >> 4) & 3;
  const int llo = tid & 15;
  const int wr = w >> 1, wc = w & 1;
  const size_t brow = (size_t)by * 128, bcol = (size_t)bx * 128;
  constexpr int ASTR = A_F32 ? 8192 : 4096;   // shorts per buffer
  constexpr int BSTR = B_F32 ? 8192 : 4096;

  auto stage = [&](int k0, int bufi) {
    if constexpr (A_F32) {
#pragma unroll
      for (int i = 0; i < 4; ++i) {
        int o = i * 256 + tid;
        int row = o >> 3, gs = (o & 7) ^ (row & 7);
        gld16((const float*)A + (brow + row) * (size_t)K + k0 + gs * 4,
              As + bufi * ASTR + (size_t)(i * 256 + w * 64) * 8);
      }
    } else {
#pragma unroll
      for (int i = 0; i < 2; ++i) {
        int o = i * 256 + tid;
        int row = o >> 2, gs = (o & 3) ^ ((row >> 1) & 3);
        gld16((const unsigned short*)A + (brow + row) * (size_t)K + k0 + gs * 8,
              As + bufi * ASTR + (size_t)(i * 256 + w * 64) * 8);
      }
    }
    if constexpr (B_F32) {
#pragma unroll
      for (int i = 0; i < 4; ++i) {
        int o = i * 256 + tid;
        int row = o >> 3, gs = (o & 7) ^ (row & 7);
        gld16((const float*)Bt + (bcol + row) * (size_t)K + k0 + gs * 4,
              Bs + bufi * BSTR + (size_t)(i * 256 + w * 64) * 8);
      }
    } else {
#pragma unroll
      for (int i = 0; i < 2; ++i) {
        int o = i * 256 + tid;
        int row = o >> 2, gs = (o & 3) ^ ((row >> 1) & 3);
        gld16((const unsigned short*)Bt + (bcol + row) * (size_t)K + k0 + gs * 8,
              Bs + bufi * BSTR + (size_t)(i * 256 + w * 64) * 8);
      }
    }
  };

  // fragment fetch: fp32-staged operand converts in-register
  auto frag_f32 = [&](const unsigned short* buf, int row) -> short8 {
    const char* p = (const char*)buf;
    int g0 = (lhi * 2) ^ (row & 7);
    float4 v0 = *reinterpret_cast<const float4*>(p + row * 128 + g0 * 16);
    float4 v1 = *reinterpret_cast<const float4*>(p + row * 128 + (g0 ^ 1) * 16);
    uint4 pk = {cvt_pk_bf16(v0.x, v0.y), cvt_pk_bf16(v0.z, v0.w),
                cvt_pk_bf16(v1.x, v1.y), cvt_pk_bf16(v1.z, v1.w)};
    return __builtin_bit_cast(short8, pk);
  };
  // bf16 fragment fetch with the matching granule XOR
  auto frag_bf = [&](const unsigned short* buf, int row) -> short8 {
    int g = lhi ^ ((row >> 1) & 3);
    return *reinterpret_cast<const short8*>((const char*)buf + row * 64 + g * 16);
  };

  floatx4 acc[4][4];
#pragma unroll
  for (int i = 0; i < 4; ++i)
#pragma unroll
    for (int j = 0; j < 4; ++j)
      acc[i][j] = (floatx4){0.f, 0.f, 0.f, 0.f};

  stage(0, 0);
  __syncthreads();
  int buf = 0;
  const int nk = K >> 5;
  for (int t = 0; t < nk; ++t) {
    if (t + 1 < nk) stage((t + 1) * 32, buf ^ 1);
    const unsigned short* Ab = As + buf * ASTR;
    const unsigned short* Bb = Bs + buf * BSTR;
    short8 a[4], b[4];
#pragma unroll
    for (int f = 0; f < 4; ++f) {
      int ra = wr * 64 + f * 16 + llo;
      int rb = wc * 64 + f * 16 + llo;
      if constexpr (A_F32)
        a[f] = frag_f32(Ab, ra);
      else
        a[f] = frag_bf(Ab, ra);
      if constexpr (B_F32)
        b[f] = frag_f32(Bb, rb);
      else
        b[f] = frag_bf(Bb, rb);
    }
    __builtin_amdgcn_s_setprio(1);
#pragma unroll
    for (int i = 0; i < 4; ++i)
#pragma unroll
      for (int j = 0; j < 4; ++j)
        acc[i][j] = __builtin_amdgcn_mfma_f32_16x16x32_bf16(a[i], b[j], acc[i][j], 0, 0, 0);
    __builtin_amdgcn_s_setprio(0);
    __syncthreads();
    buf ^= 1;
  }

#pragma unroll
  for (int i = 0; i < 4; ++i) {
#pragma unroll
    for (int j = 0; j < 4; ++j) {
      size_t gr0 = brow + wr * 64 + i * 16 + lhi * 4;
      size_t gc = bcol + wc * 64 + j * 16 + llo;
#pragma unroll
      for (int r = 0; r < 4; ++r) {
        size_t grow = gr0 + r;
        float v = acc[i][j][r];
        v += rowBias ? bias[grow] : bias[gc];
        v *= scale;
        if (OUT_F32)
          ((float*)C)[grow * N + gc] = v;
        else
          ((unsigned short*)C)[grow * N + gc] = f2bf(v);
      }
    }
  }
}

// fused Q + K + V projections; fp32 activations staged raw via global_load_lds.
// Q-seg: 2D XCD map (proven fetch reduction r14). K/V segs: r11 col-major maps.
__global__ __launch_bounds__(256) void k_gemm_qkv(
    const float* __restrict__ query, const unsigned short* __restrict__ WqT,
    const float* __restrict__ bq, unsigned short* __restrict__ qb,
    const float* __restrict__ key_in, const unsigned short* __restrict__ WkT,
    const float* __restrict__ bk, unsigned short* __restrict__ kb,
    const unsigned short* __restrict__ WvT, const float* __restrict__ value,
    const float* __restrict__ bv, unsigned short* __restrict__ vtb) {
  __shared__ __align__(16) unsigned short lds[24576];   // 48 KB
  int bid = blockIdx.x;
  if (bid < 512) {
    int xcd = bid & 7, u = bid >> 3;
    int by = (xcd >> 1) * 8 + (u & 7);
    int bx = (xcd & 1) * 8 + (u >> 3);
    gemm_bt_tile<false, true, false>(query, WqT, bq, false, qb, E_, E_,
                                     QK_SCALE * LOG2E_, bx, by,
                                     lds, lds + 16384);
  } else if (bid < 640) {
    int u = bid - 512;
    int cm = (u & 7) * 16 + (u >> 3);
    gemm_bt_tile<false, true, false>(key_in, WkT, bk, false, kb, KV_, E_, 1.0f,
                                     cm >> 5, cm & 31, lds, lds + 16384);
  } else {
    int u = bid - 640;
    int cm = (u & 7) * 16 + (u >> 3);
    gemm_bt_tile<false, false, true>(WvT, value, bv, true, vtb, BS_, E_, 1.0f,
                                     cm >> 2, cm & 3, lds, lds + 8192);
  }
}

__global__ __launch_bounds__(256) void k_gemm_o(
    const unsigned short* __restrict__ A, const unsigned short* __restrict__ Bt,
    const float* __restrict__ bias, float* __restrict__ C) {
  __shared__ __align__(16) unsigned short As[2 * 128 * 32];
  __shared__ __align__(16) unsigned short Bs[2 * 128 * 32];
  int cm = (blockIdx.x & 7) * 64 + (blockIdx.x >> 3);
  gemm_bt_tile<true, false, false>(A, Bt, bias, false, C, E_, E_, 1.0f,
                                   cm >> 5, cm & 31, As, Bs);
}

// ---------------- fused GQA flash attention (QBLK=256, 8 waves, K+V dbuf in LDS) -----
// XCD-affinity swizzle: bid%8 selects (b,g) so each XCD's L2 owns ONE KV working set.
__global__ __launch_bounds__(512) void k_attn(
    const unsigned short* __restrict__ qb, const unsigned short* __restrict__ kb,
    const unsigned short* __restrict__ vt, unsigned short* __restrict__ attn) {
  __shared__ __align__(16) unsigned short Ks[2][64 * 128];
  __shared__ __align__(16) unsigned short Vs[2][128 * 64];
  __shared__ __align__(16) unsigned short Ps[8][32 * 64];

  const int tid = threadIdx.x;
  const int w = tid >> 6;
  const int lhi = (tid >> 4) & 3;
  const int llo = tid & 15;
  const int bid = blockIdx.x;
  const int xcd = bid & 7;
  const int b = xcd >> 2, g = xcd & 3;
  const int inner = bid >> 3;
  const int hq = inner & 3, qt = inner >> 2;
  const int h = g * 4 + hq;

  char* PsW = (char*)&Ps[0][0] + w * 4096;

  short8 qf[2][4];
#pragma unroll
  for (int rt = 0; rt < 2; ++rt)
#pragma unroll
    for (int hc = 0; hc < 4; ++hc) {
      int row = qt * 256 + w * 32 + rt * 16 + llo;
      qf[rt][hc] = *reinterpret_cast<const short8*>(
          qb + ((size_t)(b * 2048 + row)) * 2048 + h * 128 + hc * 32 + lhi * 8);
    }

  floatx4 acc[2][8];
#pragma unroll
  for (int rt = 0; rt < 2; ++rt)
#pragma unroll
    for (int dc = 0; dc < 8; ++dc)
      acc[rt][dc] = (floatx4){0.f, 0.f, 0.f, 0.f};
  float m_[2] = {-1e30f, -1e30f};
  float l_[2] = {0.f, 0.f};

  auto stage = [&](int kv0, int buf) {
#pragma unroll
    for (int i = 0; i < 2; ++i) {
      int o = i * 512 + tid;
      int row = o >> 4, gr2 = (o & 15) ^ (row & 7);
      gld16(kb + ((size_t)(b * 2048 + kv0 + row)) * 512 + g * 128 + gr2 * 8,
            &Ks[buf][(size_t)(i * 512 + w * 64) * 8]);
    }
#pragma unroll
    for (int i = 0; i < 2; ++i) {
      int o = i * 512 + tid;
      int row = o >> 3, gr2 = (o & 7) ^ (row & 7);
      gld16(vt + ((size_t)(g * 128 + row)) * 4096 + b * 2048 + kv0 + gr2 * 8,
            &Vs[buf][(size_t)(i * 512 + w * 64) * 8]);
    }
  };

  stage(0, 0);
  __syncthreads();
  int buf = 0;

  for (int t = 0; t < 32; ++t) {
    const int kv0 = t * 64;
    if (t < 31) stage(kv0 + 64, buf ^ 1);

    floatx4 sc[2][4];
#pragma unroll
    for (int rt = 0; rt < 2; ++rt)
#pragma unroll
      for (int c = 0; c < 4; ++c)
        sc[rt][c] = (floatx4){0.f, 0.f, 0.f, 0.f};
    __builtin_amdgcn_s_setprio(1);
#pragma unroll
    for (int c = 0; c < 4; ++c) {
      int krow = c * 16 + llo;
#pragma unroll
      for (int hc = 0; hc < 4; ++hc) {
        int byteoff = krow * 256 + ((hc * 64 + lhi * 16) ^ ((krow & 7) << 4));
        short8 kf = *reinterpret_cast<const short8*>((const char*)&Ks[buf][0] + byteoff);
        sc[0][c] = __builtin_amdgcn_mfma_f32_16x16x32_bf16(kf, qf[0][hc], sc[0][c], 0, 0, 0);
        sc[1][c] = __builtin_amdgcn_mfma_f32_16x16x32_bf16(kf, qf[1][hc], sc[1][c], 0, 0, 0);
      }
    }
    __builtin_amdgcn_s_setprio(0);

#pragma unroll
    for (int rt = 0; rt < 2; ++rt) {
      float pm = sc[rt][0][0];
#pragma unroll
      for (int c = 0; c < 4; ++c)
#pragma unroll
        for (int r = 0; r < 4; ++r) pm = fmaxf(pm, sc[rt][c][r]);
      if (__any(pm > m_[rt] + 8.0f)) {
        float t2 = pm;
        t2 = fmaxf(t2, __shfl_xor(t2, 16));
        t2 = fmaxf(t2, __shfl_xor(t2, 32));
        float m2 = fmaxf(m_[rt], t2);
        float scr = __builtin_amdgcn_exp2f(m_[rt] - m2);
        m_[rt] = m2;
        l_[rt] *= scr;
#pragma unroll
        for (int r = 0; r < 4; ++r) {
          float s_r = __shfl(scr, (tid & 48) | (((tid >> 2) & 12) + r));
#pragma unroll
          for (int dc = 0; dc < 8; ++dc) acc[rt][dc][r] *= s_r;
        }
      }
      float lsum = l_[rt];
#pragma unroll
      for (int c = 0; c < 4; ++c) {
        float e0 = __builtin_amdgcn_exp2f(sc[rt][c][0] - m_[rt]);
        float e1 = __builtin_amdgcn_exp2f(sc[rt][c][1] - m_[rt]);
        float e2 = __builtin_amdgcn_exp2f(sc[rt][c][2] - m_[rt]);
        float e3 = __builtin_amdgcn_exp2f(sc[rt][c][3] - m_[rt]);
        lsum += (e0 + e1) + (e2 + e3);
        uint2 pk;
        pk.x = cvt_pk_bf16(e0, e1);
        pk.y = cvt_pk_bf16(e2, e3);
        int byteoff = (rt * 16 + llo) * 128 + ((c * 32 + lhi * 8) ^ ((llo & 7) << 4));
        *reinterpret_cast<uint2*>(PsW + byteoff) = pk;
      }
      l_[rt] = lsum;
    }

    short8 pf[2][2];
#pragma unroll
    for (int rt = 0; rt < 2; ++rt)
#pragma unroll
      for (int kc = 0; kc < 2; ++kc) {
        int byteoff = (rt * 16 + llo) * 128 + ((kc * 64 + lhi * 16) ^ ((llo & 7) << 4));
        pf[rt][kc] = *reinterpret_cast<const short8*>(PsW + byteoff);
      }
    __builtin_amdgcn_s_setprio(1);
#pragma unroll
    for (int dc = 0; dc < 8; ++dc) {
      int vrow = dc * 16 + llo;
      int bo0 = vrow * 128 + ((lhi * 16) ^ ((vrow & 7) << 4));
      int bo1 = vrow * 128 + ((64 + lhi * 16) ^ ((vrow & 7) << 4));
      short8 vf0 = *reinterpret_cast<const short8*>((const char*)&Vs[buf][0] + bo0);
      short8 vf1 = *reinterpret_cast<const short8*>((const char*)&Vs[buf][0] + bo1);
      acc[0][dc] = __builtin_amdgcn_mfma_f32_16x16x32_bf16(pf[0][0], vf0, acc[0][dc], 0, 0, 0);
      acc[1][dc] = __builtin_amdgcn_mfma_f32_16x16x32_bf16(pf[1][0], vf0, acc[1][dc], 0, 0, 0);
      acc[0][dc] = __builtin_amdgcn_mfma_f32_16x16x32_bf16(pf[0][1], vf1, acc[0][dc], 0, 0, 0);
      acc[1][dc] = __builtin_amdgcn_mfma_f32_16x16x32_bf16(pf[1][1], vf1, acc[1][dc], 0, 0, 0);
    }
    __builtin_amdgcn_s_setprio(0);
    __syncthreads();
    buf ^= 1;
  }

#pragma unroll
  for (int rt = 0; rt < 2; ++rt) {
    float t2 = l_[rt];
    t2 += __shfl_xor(t2, 16);
    t2 += __shfl_xor(t2, 32);
    float linv = 1.0f / t2;
    float lr[4];
#pragma unroll
    for (int r = 0; r < 4; ++r)
      lr[r] = __shfl(linv, (tid & 48) | (((tid >> 2) & 12) + r));
#pragma unroll
    for (int dc = 0; dc < 8; ++dc)
#pragma unroll
      for (int r = 0; r < 4; ++r) {
        int row = qt * 256 + w * 32 + rt * 16 + lhi * 4 + r;
        float v = acc[rt][dc][r] * lr[r];
        attn[((size_t)(b * 2048 + row)) * 2048 + h * 128 + dc * 16 + llo] = f2bf(v);
      }
  }
}

extern "C" void kernel_launch(void* const* d_in, const int* in_sizes, int n_in,
                              void* d_out, int out_size, void* d_ws, size_t ws_size,
                              hipStream_t stream) {
  const float* query  = (const float*)d_in[0];
  const float* key_in = (const float*)d_in[1];
  const float* value  = (const float*)d_in[2];
  const float* Wq = (const float*)d_in[3];
  const float* bq = (const float*)d_in[4];
  const float* Wk = (const float*)d_in[5];
  const float* bk = (const float*)d_in[6];
  const float* Wv = (const float*)d_in[7];
  const float* bv = (const float*)d_in[8];
  const float* Wo = (const float*)d_in[9];
  const float* bo = (const float*)d_in[10];
  float* out = (float*)d_out;

  char* ws = (char*)d_ws;
  size_t off = 0;
  auto alloc = [&](size_t bytes) {
    char* p = ws + off;
    off += (bytes + 255) & ~(size_t)255;
    return p;
  };
  unsigned short* WqT  = (unsigned short*)alloc((size_t)E_ * E_ * 2);
  unsigned short* WkT  = (unsigned short*)alloc((size_t)KV_ * E_ * 2);
  unsigned short* WvT  = (unsigned short*)alloc((size_t)KV_ * E_ * 2);
  unsigned short* WoT  = (unsigned short*)alloc((size_t)E_ * E_ * 2);
  unsigned short* qb   = (unsigned short*)alloc((size_t)BS_ * E_ * 2);
  unsigned short* kb   = (unsigned short*)alloc((size_t)BS_ * KV_ * 2);
  unsigned short* vtb  = (unsigned short*)alloc((size_t)KV_ * BS_ * 2);
  unsigned short* attb = (unsigned short*)alloc((size_t)BS_ * E_ * 2);

  k_prep<<<10240, 256, 0, stream>>>(Wq, WqT, Wk, WkT, Wv, WvT, Wo, WoT);
  k_gemm_qkv<<<768, 256, 0, stream>>>(query, WqT, bq, qb, key_in, WkT, bk, kb,
                                      WvT, value, bv, vtb);
  k_attn<<<B_ * NH_ * (S_ / 256), 512, 0, stream>>>(qb, kb, vtb, attb);
  k_gemm_o<<<512, 256, 0, stream>>>(attb, WoT, bo, out);
}

// Round 17
// 216.913 us; speedup vs baseline: 1.2219x; 1.0090x over previous
//
#include <hip/hip_runtime.h>
#include <hip/hip_bf16.h>

#define E_ 2048
#define S_ 2048
#define B_ 2
#define BS_ 4096
#define KV_ 512
#define NH_ 16
#define G_ 4
#define HD_ 128
#define QK_SCALE 0.08838834764831845f
#define LOG2E_ 1.4426950408889634f

typedef __attribute__((ext_vector_type(8))) short short8;
typedef __attribute__((ext_vector_type(4))) float floatx4;
typedef __attribute__((ext_vector_type(4))) unsigned short ushort4_;

static __device__ __forceinline__ unsigned short f2bf(float f) {
  unsigned int u = __builtin_bit_cast(unsigned int, f);
  u += 0x7fffu + ((u >> 16) & 1u);
  return (unsigned short)(u >> 16);
}

static __device__ __forceinline__ unsigned int cvt_pk_bf16(float lo, float hi) {
  unsigned int r;
  asm("v_cvt_pk_bf16_f32 %0, %1, %2" : "=v"(r) : "v"(lo), "v"(hi));
  return r;
}

static __device__ __forceinline__ void gld16(const void* g, void* l) {
  __builtin_amdgcn_global_load_lds(
      (const __attribute__((address_space(1))) unsigned int*)g,
      (__attribute__((address_space(3))) unsigned int*)l, 16, 0, 0);
}

// ---------------- prep: 4 weight transposes (fp32 [K][N] -> bf16 [N][K]) -------------
__global__ __launch_bounds__(256) void k_prep(
    const float* __restrict__ Wq, unsigned short* __restrict__ WqT,
    const float* __restrict__ Wk, unsigned short* __restrict__ WkT,
    const float* __restrict__ Wv, unsigned short* __restrict__ WvT,
    const float* __restrict__ Wo, unsigned short* __restrict__ WoT) {
  __shared__ float ts[32][33];
  int t = blockIdx.x;
  const float* in; unsigned short* out; int N; int rem;
  if (t < 4096)      { in = Wq; out = WqT; N = 2048; rem = t; }
  else if (t < 5120) { in = Wk; out = WkT; N = 512;  rem = t - 4096; }
  else if (t < 6144) { in = Wv; out = WvT; N = 512;  rem = t - 5120; }
  else               { in = Wo; out = WoT; N = 2048; rem = t - 6144; }
  const int K = 2048;
  int nx = N >> 5;
  int bx = rem % nx, by = rem / nx;
  int tx = threadIdx.x & 31, ty = threadIdx.x >> 5;
  int n0 = bx * 32, k0 = by * 32;
#pragma unroll
  for (int i = 0; i < 4; ++i)
    ts[ty + i * 8][tx] = in[(size_t)(k0 + ty + i * 8) * N + n0 + tx];
  __syncthreads();
#pragma unroll
  for (int i = 0; i < 4; ++i)
    out[(size_t)(n0 + ty + i * 8) * K + k0 + tx] = f2bf(ts[tx][ty + i * 8]);
}

// ------- bt-GEMM tile body (BK=32, double-buffered, 1 barrier / K-step) -------------
// A_F32 / B_F32: fp32 operand staged RAW via global_load_lds (source-granule swizzle,
// conflict-free), converted to bf16 in the fragment read. bf16 operands staged with
// source-granule swizzle g^((row>>1)&3) + matching read XOR (2-way, free).
// Epilogue: per-wave LDS bounce (f32, lhi-XOR swizzle) -> coalesced b64/b128 stores.
template <bool OUT_F32, bool A_F32, bool B_F32>
static __device__ __forceinline__ void gemm_bt_tile(
    const void* __restrict__ A, const void* __restrict__ Bt,
    const float* __restrict__ bias, bool rowBias, void* __restrict__ C,
    int N, int K, float scale, int bx, int by,
    unsigned short* As, unsigned short* Bs) {
  const int tid = threadIdx.x;
  const int w = tid >> 6;
  const int lhi = (tid >> 4) & 3;
  const int llo = tid & 15;
  const int wr = w >> 1, wc = w & 1;
  const size_t brow = (size_t)by * 128, bcol = (size_t)bx * 128;
  constexpr int ASTR = A_F32 ? 8192 : 4096;   // shorts per buffer
  constexpr int BSTR = B_F32 ? 8192 : 4096;

  auto stage = [&](int k0, int bufi) {
    if constexpr (A_F32) {
#pragma unroll
      for (int i = 0; i < 4; ++i) {
        int o = i * 256 + tid;
        int row = o >> 3, gs = (o & 7) ^ (row & 7);
        gld16((const float*)A + (brow + row) * (size_t)K + k0 + gs * 4,
              As + bufi * ASTR + (size_t)(i * 256 + w * 64) * 8);
      }
    } else {
#pragma unroll
      for (int i = 0; i < 2; ++i) {
        int o = i * 256 + tid;
        int row = o >> 2, gs = (o & 3) ^ ((row >> 1) & 3);
        gld16((const unsigned short*)A + (brow + row) * (size_t)K + k0 + gs * 8,
              As + bufi * ASTR + (size_t)(i * 256 + w * 64) * 8);
      }
    }
    if constexpr (B_F32) {
#pragma unroll
      for (int i = 0; i < 4; ++i) {
        int o = i * 256 + tid;
        int row = o >> 3, gs = (o & 7) ^ (row & 7);
        gld16((const float*)Bt + (bcol + row) * (size_t)K + k0 + gs * 4,
              Bs + bufi * BSTR + (size_t)(i * 256 + w * 64) * 8);
      }
    } else {
#pragma unroll
      for (int i = 0; i < 2; ++i) {
        int o = i * 256 + tid;
        int row = o >> 2, gs = (o & 3) ^ ((row >> 1) & 3);
        gld16((const unsigned short*)Bt + (bcol + row) * (size_t)K + k0 + gs * 8,
              Bs + bufi * BSTR + (size_t)(i * 256 + w * 64) * 8);
      }
    }
  };

  auto frag_f32 = [&](const unsigned short* buf, int row) -> short8 {
    const char* p = (const char*)buf;
    int g0 = (lhi * 2) ^ (row & 7);
    float4 v0 = *reinterpret_cast<const float4*>(p + row * 128 + g0 * 16);
    float4 v1 = *reinterpret_cast<const float4*>(p + row * 128 + (g0 ^ 1) * 16);
    uint4 pk = {cvt_pk_bf16(v0.x, v0.y), cvt_pk_bf16(v0.z, v0.w),
                cvt_pk_bf16(v1.x, v1.y), cvt_pk_bf16(v1.z, v1.w)};
    return __builtin_bit_cast(short8, pk);
  };
  auto frag_bf = [&](const unsigned short* buf, int row) -> short8 {
    int g = lhi ^ ((row >> 1) & 3);
    return *reinterpret_cast<const short8*>((const char*)buf + row * 64 + g * 16);
  };

  floatx4 acc[4][4];
#pragma unroll
  for (int i = 0; i < 4; ++i)
#pragma unroll
    for (int j = 0; j < 4; ++j)
      acc[i][j] = (floatx4){0.f, 0.f, 0.f, 0.f};

  stage(0, 0);
  __syncthreads();
  int buf = 0;
  const int nk = K >> 5;
  for (int t = 0; t < nk; ++t) {
    if (t + 1 < nk) stage((t + 1) * 32, buf ^ 1);
    const unsigned short* Ab = As + buf * ASTR;
    const unsigned short* Bb = Bs + buf * BSTR;
    short8 a[4], b[4];
#pragma unroll
    for (int f = 0; f < 4; ++f) {
      int ra = wr * 64 + f * 16 + llo;
      int rb = wc * 64 + f * 16 + llo;
      if constexpr (A_F32)
        a[f] = frag_f32(Ab, ra);
      else
        a[f] = frag_bf(Ab, ra);
      if constexpr (B_F32)
        b[f] = frag_f32(Bb, rb);
      else
        b[f] = frag_bf(Bb, rb);
    }
    __builtin_amdgcn_s_setprio(1);
#pragma unroll
    for (int i = 0; i < 4; ++i)
#pragma unroll
      for (int j = 0; j < 4; ++j)
        acc[i][j] = __builtin_amdgcn_mfma_f32_16x16x32_bf16(a[i], b[j], acc[i][j], 0, 0, 0);
    __builtin_amdgcn_s_setprio(0);
    __syncthreads();
    buf ^= 1;
  }

  // ---- vectorized epilogue: per-wave 8KB f32 LDS bounce, 2 halves of 32 rows ----
  // (runs after the K-loop's final barrier; regions are wave-private)
  float* reg = reinterpret_cast<float*>(As) + w * 2048;
#pragma unroll
  for (int h = 0; h < 2; ++h) {
#pragma unroll
    for (int i2 = 0; i2 < 2; ++i2) {
      int i = h * 2 + i2;
#pragma unroll
      for (int j = 0; j < 4; ++j) {
#pragma unroll
        for (int r = 0; r < 4; ++r) {
          int row32 = i2 * 16 + lhi * 4 + r;
          int colx = (j * 16 + llo) ^ (lhi * 16);
          size_t grow = brow + wr * 64 + h * 32 + row32;
          size_t gc = bcol + wc * 64 + j * 16 + llo;
          float v = acc[i][j][r];
          v += rowBias ? bias[grow] : bias[gc];
          v *= scale;
          reg[row32 * 64 + colx] = v;
        }
      }
    }
#pragma unroll
    for (int p = 0; p < 8; ++p) {
      int r4 = (tid & 63) >> 4;
      int ch = tid & 15;
      int row32 = p * 4 + r4;
      int colx = (ch * 4) ^ ((p & 3) * 16);
      float4 v4 = *reinterpret_cast<const float4*>(reg + row32 * 64 + colx);
      size_t grow = brow + wr * 64 + h * 32 + row32;
      size_t gc = bcol + wc * 64 + ch * 4;
      if constexpr (OUT_F32) {
        *reinterpret_cast<float4*>((float*)C + grow * N + gc) = v4;
      } else {
        uint2 pk2;
        pk2.x = cvt_pk_bf16(v4.x, v4.y);
        pk2.y = cvt_pk_bf16(v4.z, v4.w);
        *reinterpret_cast<uint2*>((unsigned short*)C + grow * N + gc) = pk2;
      }
    }
  }
}

// fused Q + K + V projections; fp32 activations staged raw via global_load_lds.
// Q-seg: 2D XCD map (proven fetch reduction r14). K/V segs: r11 col-major maps.
__global__ __launch_bounds__(256) void k_gemm_qkv(
    const float* __restrict__ query, const unsigned short* __restrict__ WqT,
    const float* __restrict__ bq, unsigned short* __restrict__ qb,
    const float* __restrict__ key_in, const unsigned short* __restrict__ WkT,
    const float* __restrict__ bk, unsigned short* __restrict__ kb,
    const unsigned short* __restrict__ WvT, const float* __restrict__ value,
    const float* __restrict__ bv, unsigned short* __restrict__ vtb) {
  __shared__ __align__(16) unsigned short lds[24576];   // 48 KB
  int bid = blockIdx.x;
  if (bid < 512) {
    int xcd = bid & 7, u = bid >> 3;
    int by = (xcd >> 1) * 8 + (u & 7);
    int bx = (xcd & 1) * 8 + (u >> 3);
    gemm_bt_tile<false, true, false>(query, WqT, bq, false, qb, E_, E_,
                                     QK_SCALE * LOG2E_, bx, by,
                                     lds, lds + 16384);
  } else if (bid < 640) {
    int u = bid - 512;
    int cm = (u & 7) * 16 + (u >> 3);
    gemm_bt_tile<false, true, false>(key_in, WkT, bk, false, kb, KV_, E_, 1.0f,
                                     cm >> 5, cm & 31, lds, lds + 16384);
  } else {
    int u = bid - 640;
    int cm = (u & 7) * 16 + (u >> 3);
    gemm_bt_tile<false, false, true>(WvT, value, bv, true, vtb, BS_, E_, 1.0f,
                                     cm >> 2, cm & 3, lds, lds + 8192);
  }
}

__global__ __launch_bounds__(256) void k_gemm_o(
    const unsigned short* __restrict__ A, const unsigned short* __restrict__ Bt,
    const float* __restrict__ bias, float* __restrict__ C) {
  __shared__ __align__(16) unsigned short lds[16384];   // 32 KB
  int cm = (blockIdx.x & 7) * 64 + (blockIdx.x >> 3);
  gemm_bt_tile<true, false, false>(A, Bt, bias, false, C, E_, E_, 1.0f,
                                   cm >> 5, cm & 31, lds, lds + 8192);
}

// ---------------- fused GQA flash attention (QBLK=256, 8 waves, K+V dbuf in LDS) -----
// XCD-affinity swizzle: bid%8 selects (b,g) so each XCD's L2 owns ONE KV working set.
__global__ __launch_bounds__(512) void k_attn(
    const unsigned short* __restrict__ qb, const unsigned short* __restrict__ kb,
    const unsigned short* __restrict__ vt, unsigned short* __restrict__ attn) {
  __shared__ __align__(16) unsigned short Ks[2][64 * 128];
  __shared__ __align__(16) unsigned short Vs[2][128 * 64];
  __shared__ __align__(16) unsigned short Ps[8][32 * 64];

  const int tid = threadIdx.x;
  const int w = tid >> 6;
  const int lhi = (tid >> 4) & 3;
  const int llo = tid & 15;
  const int bid = blockIdx.x;
  const int xcd = bid & 7;
  const int b = xcd >> 2, g = xcd & 3;
  const int inner = bid >> 3;
  const int hq = inner & 3, qt = inner >> 2;
  const int h = g * 4 + hq;

  char* PsW = (char*)&Ps[0][0] + w * 4096;

  short8 qf[2][4];
#pragma unroll
  for (int rt = 0; rt < 2; ++rt)
#pragma unroll
    for (int hc = 0; hc < 4; ++hc) {
      int row = qt * 256 + w * 32 + rt * 16 + llo;
      qf[rt][hc] = *reinterpret_cast<const short8*>(
          qb + ((size_t)(b * 2048 + row)) * 2048 + h * 128 + hc * 32 + lhi * 8);
    }

  floatx4 acc[2][8];
#pragma unroll
  for (int rt = 0; rt < 2; ++rt)
#pragma unroll
    for (int dc = 0; dc < 8; ++dc)
      acc[rt][dc] = (floatx4){0.f, 0.f, 0.f, 0.f};
  float m_[2] = {-1e30f, -1e30f};
  float l_[2] = {0.f, 0.f};

  auto stage = [&](int kv0, int buf) {
#pragma unroll
    for (int i = 0; i < 2; ++i) {
      int o = i * 512 + tid;
      int row = o >> 4, gr2 = (o & 15) ^ (row & 7);
      gld16(kb + ((size_t)(b * 2048 + kv0 + row)) * 512 + g * 128 + gr2 * 8,
            &Ks[buf][(size_t)(i * 512 + w * 64) * 8]);
    }
#pragma unroll
    for (int i = 0; i < 2; ++i) {
      int o = i * 512 + tid;
      int row = o >> 3, gr2 = (o & 7) ^ (row & 7);
      gld16(vt + ((size_t)(g * 128 + row)) * 4096 + b * 2048 + kv0 + gr2 * 8,
            &Vs[buf][(size_t)(i * 512 + w * 64) * 8]);
    }
  };

  stage(0, 0);
  __syncthreads();
  int buf = 0;

  for (int t = 0; t < 32; ++t) {
    const int kv0 = t * 64;
    if (t < 31) stage(kv0 + 64, buf ^ 1);

    floatx4 sc[2][4];
#pragma unroll
    for (int rt = 0; rt < 2; ++rt)
#pragma unroll
      for (int c = 0; c < 4; ++c)
        sc[rt][c] = (floatx4){0.f, 0.f, 0.f, 0.f};
    __builtin_amdgcn_s_setprio(1);
#pragma unroll
    for (int c = 0; c < 4; ++c) {
      int krow = c * 16 + llo;
#pragma unroll
      for (int hc = 0; hc < 4; ++hc) {
        int byteoff = krow * 256 + ((hc * 64 + lhi * 16) ^ ((krow & 7) << 4));
        short8 kf = *reinterpret_cast<const short8*>((const char*)&Ks[buf][0] + byteoff);
        sc[0][c] = __builtin_amdgcn_mfma_f32_16x16x32_bf16(kf, qf[0][hc], sc[0][c], 0, 0, 0);
        sc[1][c] = __builtin_amdgcn_mfma_f32_16x16x32_bf16(kf, qf[1][hc], sc[1][c], 0, 0, 0);
      }
    }
    __builtin_amdgcn_s_setprio(0);

#pragma unroll
    for (int rt = 0; rt < 2; ++rt) {
      float pm = sc[rt][0][0];
#pragma unroll
      for (int c = 0; c < 4; ++c)
#pragma unroll
        for (int r = 0; r < 4; ++r) pm = fmaxf(pm, sc[rt][c][r]);
      if (__any(pm > m_[rt] + 8.0f)) {
        float t2 = pm;
        t2 = fmaxf(t2, __shfl_xor(t2, 16));
        t2 = fmaxf(t2, __shfl_xor(t2, 32));
        float m2 = fmaxf(m_[rt], t2);
        float scr = __builtin_amdgcn_exp2f(m_[rt] - m2);
        m_[rt] = m2;
        l_[rt] *= scr;
#pragma unroll
        for (int r = 0; r < 4; ++r) {
          float s_r = __shfl(scr, (tid & 48) | (((tid >> 2) & 12) + r));
#pragma unroll
          for (int dc = 0; dc < 8; ++dc) acc[rt][dc][r] *= s_r;
        }
      }
      float lsum = l_[rt];
#pragma unroll
      for (int c = 0; c < 4; ++c) {
        float e0 = __builtin_amdgcn_exp2f(sc[rt][c][0] - m_[rt]);
        float e1 = __builtin_amdgcn_exp2f(sc[rt][c][1] - m_[rt]);
        float e2 = __builtin_amdgcn_exp2f(sc[rt][c][2] - m_[rt]);
        float e3 = __builtin_amdgcn_exp2f(sc[rt][c][3] - m_[rt]);
        lsum += (e0 + e1) + (e2 + e3);
        uint2 pk;
        pk.x = cvt_pk_bf16(e0, e1);
        pk.y = cvt_pk_bf16(e2, e3);
        int byteoff = (rt * 16 + llo) * 128 + ((c * 32 + lhi * 8) ^ ((llo & 7) << 4));
        *reinterpret_cast<uint2*>(PsW + byteoff) = pk;
      }
      l_[rt] = lsum;
    }

    short8 pf[2][2];
#pragma unroll
    for (int rt = 0; rt < 2; ++rt)
#pragma unroll
      for (int kc = 0; kc < 2; ++kc) {
        int byteoff = (rt * 16 + llo) * 128 + ((kc * 64 + lhi * 16) ^ ((llo & 7) << 4));
        pf[rt][kc] = *reinterpret_cast<const short8*>(PsW + byteoff);
      }
    __builtin_amdgcn_s_setprio(1);
#pragma unroll
    for (int dc = 0; dc < 8; ++dc) {
      int vrow = dc * 16 + llo;
      int bo0 = vrow * 128 + ((lhi * 16) ^ ((vrow & 7) << 4));
      int bo1 = vrow * 128 + ((64 + lhi * 16) ^ ((vrow & 7) << 4));
      short8 vf0 = *reinterpret_cast<const short8*>((const char*)&Vs[buf][0] + bo0);
      short8 vf1 = *reinterpret_cast<const short8*>((const char*)&Vs[buf][0] + bo1);
      acc[0][dc] = __builtin_amdgcn_mfma_f32_16x16x32_bf16(pf[0][0], vf0, acc[0][dc], 0, 0, 0);
      acc[1][dc] = __builtin_amdgcn_mfma_f32_16x16x32_bf16(pf[1][0], vf0, acc[1][dc], 0, 0, 0);
      acc[0][dc] = __builtin_amdgcn_mfma_f32_16x16x32_bf16(pf[0][1], vf1, acc[0][dc], 0, 0, 0);
      acc[1][dc] = __builtin_amdgcn_mfma_f32_16x16x32_bf16(pf[1][1], vf1, acc[1][dc], 0, 0, 0);
    }
    __builtin_amdgcn_s_setprio(0);
    __syncthreads();
    buf ^= 1;
  }

#pragma unroll
  for (int rt = 0; rt < 2; ++rt) {
    float t2 = l_[rt];
    t2 += __shfl_xor(t2, 16);
    t2 += __shfl_xor(t2, 32);
    float linv = 1.0f / t2;
    float lr[4];
#pragma unroll
    for (int r = 0; r < 4; ++r)
      lr[r] = __shfl(linv, (tid & 48) | (((tid >> 2) & 12) + r));
#pragma unroll
    for (int dc = 0; dc < 8; ++dc)
#pragma unroll
      for (int r = 0; r < 4; ++r) {
        int row = qt * 256 + w * 32 + rt * 16 + lhi * 4 + r;
        float v = acc[rt][dc][r] * lr[r];
        attn[((size_t)(b * 2048 + row)) * 2048 + h * 128 + dc * 16 + llo] = f2bf(v);
      }
  }
}

extern "C" void kernel_launch(void* const* d_in, const int* in_sizes, int n_in,
                              void* d_out, int out_size, void* d_ws, size_t ws_size,
                              hipStream_t stream) {
  const float* query  = (const float*)d_in[0];
  const float* key_in = (const float*)d_in[1];
  const float* value  = (const float*)d_in[2];
  const float* Wq = (const float*)d_in[3];
  const float* bq = (const float*)d_in[4];
  const float* Wk = (const float*)d_in[5];
  const float* bk = (const float*)d_in[6];
  const float* Wv = (const float*)d_in[7];
  const float* bv = (const float*)d_in[8];
  const float* Wo = (const float*)d_in[9];
  const float* bo = (const float*)d_in[10];
  float* out = (float*)d_out;

  char* ws = (char*)d_ws;
  size_t off = 0;
  auto alloc = [&](size_t bytes) {
    char* p = ws + off;
    off += (bytes + 255) & ~(size_t)255;
    return p;
  };
  unsigned short* WqT  = (unsigned short*)alloc((size_t)E_ * E_ * 2);
  unsigned short* WkT  = (unsigned short*)alloc((size_t)KV_ * E_ * 2);
  unsigned short* WvT  = (unsigned short*)alloc((size_t)KV_ * E_ * 2);
  unsigned short* WoT  = (unsigned short*)alloc((size_t)E_ * E_ * 2);
  unsigned short* qb   = (unsigned short*)alloc((size_t)BS_ * E_ * 2);
  unsigned short* kb   = (unsigned short*)alloc((size_t)BS_ * KV_ * 2);
  unsigned short* vtb  = (unsigned short*)alloc((size_t)KV_ * BS_ * 2);
  unsigned short* attb = (unsigned short*)alloc((size_t)BS_ * E_ * 2);

  k_prep<<<10240, 256, 0, stream>>>(Wq, WqT, Wk, WkT, Wv, WvT, Wo, WoT);
  k_gemm_qkv<<<768, 256, 0, stream>>>(query, WqT, bq, qb, key_in, WkT, bk, kb,
                                      WvT, value, bv, vtb);
  k_attn<<<B_ * NH_ * (S_ / 256), 512, 0, stream>>>(qb, kb, vtb, attb);
  k_gemm_o<<<512, 256, 0, stream>>>(attb, WoT, bo, out);
}

// Round 20
// 215.495 us; speedup vs baseline: 1.2300x; 1.0066x over previous
//
#include <hip/hip_runtime.h>
#include <hip/hip_bf16.h>

#define E_ 2048
#define S_ 2048
#define B_ 2
#define BS_ 4096
#define KV_ 512
#define NH_ 16
#define G_ 4
#define HD_ 128
#define QK_SCALE 0.08838834764831845f
#define LOG2E_ 1.4426950408889634f

typedef __attribute__((ext_vector_type(8))) short short8;
typedef __attribute__((ext_vector_type(4))) float floatx4;
typedef __attribute__((ext_vector_type(4))) unsigned short ushort4_;

static __device__ __forceinline__ unsigned short f2bf(float f) {
  unsigned int u = __builtin_bit_cast(unsigned int, f);
  u += 0x7fffu + ((u >> 16) & 1u);
  return (unsigned short)(u >> 16);
}

static __device__ __forceinline__ unsigned int cvt_pk_bf16(float lo, float hi) {
  unsigned int r;
  asm("v_cvt_pk_bf16_f32 %0, %1, %2" : "=v"(r) : "v"(lo), "v"(hi));
  return r;
}

static __device__ __forceinline__ void gld16(const void* g, void* l) {
  __builtin_amdgcn_global_load_lds(
      (const __attribute__((address_space(1))) unsigned int*)g,
      (__attribute__((address_space(3))) unsigned int*)l, 16, 0, 0);
}

// ---------------- prep: 4 weight transposes (fp32 [K][N] -> bf16 [N][K]) -------------
__global__ __launch_bounds__(256) void k_prep(
    const float* __restrict__ Wq, unsigned short* __restrict__ WqT,
    const float* __restrict__ Wk, unsigned short* __restrict__ WkT,
    const float* __restrict__ Wv, unsigned short* __restrict__ WvT,
    const float* __restrict__ Wo, unsigned short* __restrict__ WoT) {
  __shared__ float ts[32][33];
  int t = blockIdx.x;
  const float* in; unsigned short* out; int N; int rem;
  if (t < 4096)      { in = Wq; out = WqT; N = 2048; rem = t; }
  else if (t < 5120) { in = Wk; out = WkT; N = 512;  rem = t - 4096; }
  else if (t < 6144) { in = Wv; out = WvT; N = 512;  rem = t - 5120; }
  else               { in = Wo; out = WoT; N = 2048; rem = t - 6144; }
  const int K = 2048;
  int nx = N >> 5;
  int bx = rem % nx, by = rem / nx;
  int tx = threadIdx.x & 31, ty = threadIdx.x >> 5;
  int n0 = bx * 32, k0 = by * 32;
#pragma unroll
  for (int i = 0; i < 4; ++i)
    ts[ty + i * 8][tx] = in[(size_t)(k0 + ty + i * 8) * N + n0 + tx];
  __syncthreads();
#pragma unroll
  for (int i = 0; i < 4; ++i)
    out[(size_t)(n0 + ty + i * 8) * K + k0 + tx] = f2bf(ts[tx][ty + i * 8]);
}

// ------- bt-GEMM tile body (BK=32, double-buffered, 1 barrier / K-step) -------------
template <bool OUT_F32, bool A_F32, bool B_F32>
static __device__ __forceinline__ void gemm_bt_tile(
    const void* __restrict__ A, const void* __restrict__ Bt,
    const float* __restrict__ bias, bool rowBias, void* __restrict__ C,
    int N, int K, float scale, int bx, int by,
    unsigned short* As, unsigned short* Bs) {
  const int tid = threadIdx.x;
  const int w = tid >> 6;
  const int lhi = (tid >> 4) & 3;
  const int llo = tid & 15;
  const int wr = w >> 1, wc = w & 1;
  const size_t brow = (size_t)by * 128, bcol = (size_t)bx * 128;
  constexpr int ASTR = A_F32 ? 8192 : 4096;
  constexpr int BSTR = B_F32 ? 8192 : 4096;

  auto stage = [&](int k0, int bufi) {
    if constexpr (A_F32) {
#pragma unroll
      for (int i = 0; i < 4; ++i) {
        int o = i * 256 + tid;
        int row = o >> 3, gs = (o & 7) ^ (row & 7);
        gld16((const float*)A + (brow + row) * (size_t)K + k0 + gs * 4,
              As + bufi * ASTR + (size_t)(i * 256 + w * 64) * 8);
      }
    } else {
#pragma unroll
      for (int i = 0; i < 2; ++i) {
        int o = i * 256 + tid;
        int row = o >> 2, gs = (o & 3) ^ ((row >> 1) & 3);
        gld16((const unsigned short*)A + (brow + row) * (size_t)K + k0 + gs * 8,
              As + bufi * ASTR + (size_t)(i * 256 + w * 64) * 8);
      }
    }
    if constexpr (B_F32) {
#pragma unroll
      for (int i = 0; i < 4; ++i) {
        int o = i * 256 + tid;
        int row = o >> 3, gs = (o & 7) ^ (row & 7);
        gld16((const float*)Bt + (bcol + row) * (size_t)K + k0 + gs * 4,
              Bs + bufi * BSTR + (size_t)(i * 256 + w * 64) * 8);
      }
    } else {
#pragma unroll
      for (int i = 0; i < 2; ++i) {
        int o = i * 256 + tid;
        int row = o >> 2, gs = (o & 3) ^ ((row >> 1) & 3);
        gld16((const unsigned short*)Bt + (bcol + row) * (size_t)K + k0 + gs * 8,
              Bs + bufi * BSTR + (size_t)(i * 256 + w * 64) * 8);
      }
    }
  };

  auto frag_f32 = [&](const unsigned short* buf, int row) -> short8 {
    const char* p = (const char*)buf;
    int g0 = (lhi * 2) ^ (row & 7);
    float4 v0 = *reinterpret_cast<const float4*>(p + row * 128 + g0 * 16);
    float4 v1 = *reinterpret_cast<const float4*>(p + row * 128 + (g0 ^ 1) * 16);
    uint4 pk = {cvt_pk_bf16(v0.x, v0.y), cvt_pk_bf16(v0.z, v0.w),
                cvt_pk_bf16(v1.x, v1.y), cvt_pk_bf16(v1.z, v1.w)};
    return __builtin_bit_cast(short8, pk);
  };
  auto frag_bf = [&](const unsigned short* buf, int row) -> short8 {
    int g = lhi ^ ((row >> 1) & 3);
    return *reinterpret_cast<const short8*>((const char*)buf + row * 64 + g * 16);
  };

  floatx4 acc[4][4];
#pragma unroll
  for (int i = 0; i < 4; ++i)
#pragma unroll
    for (int j = 0; j < 4; ++j)
      acc[i][j] = (floatx4){0.f, 0.f, 0.f, 0.f};

  stage(0, 0);
  __syncthreads();
  int buf = 0;
  const int nk = K >> 5;
  for (int t = 0; t < nk; ++t) {
    if (t + 1 < nk) stage((t + 1) * 32, buf ^ 1);
    const unsigned short* Ab = As + buf * ASTR;
    const unsigned short* Bb = Bs + buf * BSTR;
    short8 a[4], b[4];
#pragma unroll
    for (int f = 0; f < 4; ++f) {
      int ra = wr * 64 + f * 16 + llo;
      int rb = wc * 64 + f * 16 + llo;
      if constexpr (A_F32)
        a[f] = frag_f32(Ab, ra);
      else
        a[f] = frag_bf(Ab, ra);
      if constexpr (B_F32)
        b[f] = frag_f32(Bb, rb);
      else
        b[f] = frag_bf(Bb, rb);
    }
    __builtin_amdgcn_s_setprio(1);
#pragma unroll
    for (int i = 0; i < 4; ++i)
#pragma unroll
      for (int j = 0; j < 4; ++j)
        acc[i][j] = __builtin_amdgcn_mfma_f32_16x16x32_bf16(a[i], b[j], acc[i][j], 0, 0, 0);
    __builtin_amdgcn_s_setprio(0);
    __syncthreads();
    buf ^= 1;
  }

  // ---- vectorized epilogue: per-wave 8KB f32 LDS bounce ----
  float* reg = reinterpret_cast<float*>(As) + w * 2048;
#pragma unroll
  for (int h = 0; h < 2; ++h) {
#pragma unroll
    for (int i2 = 0; i2 < 2; ++i2) {
      int i = h * 2 + i2;
#pragma unroll
      for (int j = 0; j < 4; ++j) {
#pragma unroll
        for (int r = 0; r < 4; ++r) {
          int row32 = i2 * 16 + lhi * 4 + r;
          int colx = (j * 16 + llo) ^ (lhi * 16);
          size_t grow = brow + wr * 64 + h * 32 + row32;
          size_t gc = bcol + wc * 64 + j * 16 + llo;
          float v = acc[i][j][r];
          v += rowBias ? bias[grow] : bias[gc];
          v *= scale;
          reg[row32 * 64 + colx] = v;
        }
      }
    }
#pragma unroll
    for (int p = 0; p < 8; ++p) {
      int r4 = (tid & 63) >> 4;
      int ch = tid & 15;
      int row32 = p * 4 + r4;
      int colx = (ch * 4) ^ ((p & 3) * 16);
      float4 v4 = *reinterpret_cast<const float4*>(reg + row32 * 64 + colx);
      size_t grow = brow + wr * 64 + h * 32 + row32;
      size_t gc = bcol + wc * 64 + ch * 4;
      if constexpr (OUT_F32) {
        *reinterpret_cast<float4*>((float*)C + grow * N + gc) = v4;
      } else {
        uint2 pk2;
        pk2.x = cvt_pk_bf16(v4.x, v4.y);
        pk2.y = cvt_pk_bf16(v4.z, v4.w);
        *reinterpret_cast<uint2*>((unsigned short*)C + grow * N + gc) = pk2;
      }
    }
  }
}

// fused Q + K + V projections; fp32 activations staged raw via global_load_lds.
__global__ __launch_bounds__(256) void k_gemm_qkv(
    const float* __restrict__ query, const unsigned short* __restrict__ WqT,
    const float* __restrict__ bq, unsigned short* __restrict__ qb,
    const float* __restrict__ key_in, const unsigned short* __restrict__ WkT,
    const float* __restrict__ bk, unsigned short* __restrict__ kb,
    const unsigned short* __restrict__ WvT, const float* __restrict__ value,
    const float* __restrict__ bv, unsigned short* __restrict__ vtb) {
  __shared__ __align__(16) unsigned short lds[24576];   // 48 KB
  int bid = blockIdx.x;
  if (bid < 512) {
    int xcd = bid & 7, u = bid >> 3;
    int by = (xcd >> 1) * 8 + (u & 7);
    int bx = (xcd & 1) * 8 + (u >> 3);
    gemm_bt_tile<false, true, false>(query, WqT, bq, false, qb, E_, E_,
                                     QK_SCALE * LOG2E_, bx, by,
                                     lds, lds + 16384);
  } else if (bid < 640) {
    int u = bid - 512;
    int cm = (u & 7) * 16 + (u >> 3);
    gemm_bt_tile<false, true, false>(key_in, WkT, bk, false, kb, KV_, E_, 1.0f,
                                     cm >> 5, cm & 31, lds, lds + 16384);
  } else {
    int u = bid - 640;
    int cm = (u & 7) * 16 + (u >> 3);
    gemm_bt_tile<false, false, true>(WvT, value, bv, true, vtb, BS_, E_, 1.0f,
                                     cm >> 2, cm & 3, lds, lds + 8192);
  }
}

__global__ __launch_bounds__(256) void k_gemm_o(
    const unsigned short* __restrict__ A, const unsigned short* __restrict__ Bt,
    const float* __restrict__ bias, float* __restrict__ C) {
  __shared__ __align__(16) unsigned short lds[16384];   // 32 KB
  int cm = (blockIdx.x & 7) * 64 + (blockIdx.x >> 3);
  gemm_bt_tile<true, false, false>(A, Bt, bias, false, C, E_, E_, 1.0f,
                                   cm >> 5, cm & 31, lds, lds + 8192);
}

// ---------------- fused GQA flash attention (QBLK=256, 8 waves, K+V dbuf in LDS) -----
// XCD-affinity swizzle: bid%8 selects (b,g) so each XCD's L2 owns ONE KV working set.
// Epilogue vectorized via the (then-free) per-wave Ps region: bf16 bounce with 32B
// granule XOR swizzle -> 8x16B coalesced stores per thread instead of 64x2B scalars.
__global__ __launch_bounds__(512) void k_attn(
    const unsigned short* __restrict__ qb, const unsigned short* __restrict__ kb,
    const unsigned short* __restrict__ vt, unsigned short* __restrict__ attn) {
  __shared__ __align__(16) unsigned short Ks[2][64 * 128];
  __shared__ __align__(16) unsigned short Vs[2][128 * 64];
  __shared__ __align__(16) unsigned short Ps[8][32 * 64];

  const int tid = threadIdx.x;
  const int w = tid >> 6;
  const int lhi = (tid >> 4) & 3;
  const int llo = tid & 15;
  const int bid = blockIdx.x;
  const int xcd = bid & 7;
  const int b = xcd >> 2, g = xcd & 3;
  const int inner = bid >> 3;
  const int hq = inner & 3, qt = inner >> 2;
  const int h = g * 4 + hq;

  char* PsW = (char*)&Ps[0][0] + w * 4096;

  short8 qf[2][4];
#pragma unroll
  for (int rt = 0; rt < 2; ++rt)
#pragma unroll
    for (int hc = 0; hc < 4; ++hc) {
      int row = qt * 256 + w * 32 + rt * 16 + llo;
      qf[rt][hc] = *reinterpret_cast<const short8*>(
          qb + ((size_t)(b * 2048 + row)) * 2048 + h * 128 + hc * 32 + lhi * 8);
    }

  floatx4 acc[2][8];
#pragma unroll
  for (int rt = 0; rt < 2; ++rt)
#pragma unroll
    for (int dc = 0; dc < 8; ++dc)
      acc[rt][dc] = (floatx4){0.f, 0.f, 0.f, 0.f};
  float m_[2] = {-1e30f, -1e30f};
  float l_[2] = {0.f, 0.f};

  auto stage = [&](int kv0, int buf) {
#pragma unroll
    for (int i = 0; i < 2; ++i) {
      int o = i * 512 + tid;
      int row = o >> 4, gr2 = (o & 15) ^ (row & 7);
      gld16(kb + ((size_t)(b * 2048 + kv0 + row)) * 512 + g * 128 + gr2 * 8,
            &Ks[buf][(size_t)(i * 512 + w * 64) * 8]);
    }
#pragma unroll
    for (int i = 0; i < 2; ++i) {
      int o = i * 512 + tid;
      int row = o >> 3, gr2 = (o & 7) ^ (row & 7);
      gld16(vt + ((size_t)(g * 128 + row)) * 4096 + b * 2048 + kv0 + gr2 * 8,
            &Vs[buf][(size_t)(i * 512 + w * 64) * 8]);
    }
  };

  stage(0, 0);
  __syncthreads();
  int buf = 0;

  for (int t = 0; t < 32; ++t) {
    const int kv0 = t * 64;
    if (t < 31) stage(kv0 + 64, buf ^ 1);

    floatx4 sc[2][4];
#pragma unroll
    for (int rt = 0; rt < 2; ++rt)
#pragma unroll
      for (int c = 0; c < 4; ++c)
        sc[rt][c] = (floatx4){0.f, 0.f, 0.f, 0.f};
    __builtin_amdgcn_s_setprio(1);
#pragma unroll
    for (int c = 0; c < 4; ++c) {
      int krow = c * 16 + llo;
#pragma unroll
      for (int hc = 0; hc < 4; ++hc) {
        int byteoff = krow * 256 + ((hc * 64 + lhi * 16) ^ ((krow & 7) << 4));
        short8 kf = *reinterpret_cast<const short8*>((const char*)&Ks[buf][0] + byteoff);
        sc[0][c] = __builtin_amdgcn_mfma_f32_16x16x32_bf16(kf, qf[0][hc], sc[0][c], 0, 0, 0);
        sc[1][c] = __builtin_amdgcn_mfma_f32_16x16x32_bf16(kf, qf[1][hc], sc[1][c], 0, 0, 0);
      }
    }
    __builtin_amdgcn_s_setprio(0);

#pragma unroll
    for (int rt = 0; rt < 2; ++rt) {
      float pm = sc[rt][0][0];
#pragma unroll
      for (int c = 0; c < 4; ++c)
#pragma unroll
        for (int r = 0; r < 4; ++r) pm = fmaxf(pm, sc[rt][c][r]);
      if (__any(pm > m_[rt] + 8.0f)) {
        float t2 = pm;
        t2 = fmaxf(t2, __shfl_xor(t2, 16));
        t2 = fmaxf(t2, __shfl_xor(t2, 32));
        float m2 = fmaxf(m_[rt], t2);
        float scr = __builtin_amdgcn_exp2f(m_[rt] - m2);
        m_[rt] = m2;
        l_[rt] *= scr;
#pragma unroll
        for (int r = 0; r < 4; ++r) {
          float s_r = __shfl(scr, (tid & 48) | (((tid >> 2) & 12) + r));
#pragma unroll
          for (int dc = 0; dc < 8; ++dc) acc[rt][dc][r] *= s_r;
        }
      }
      float lsum = l_[rt];
#pragma unroll
      for (int c = 0; c < 4; ++c) {
        float e0 = __builtin_amdgcn_exp2f(sc[rt][c][0] - m_[rt]);
        float e1 = __builtin_amdgcn_exp2f(sc[rt][c][1] - m_[rt]);
        float e2 = __builtin_amdgcn_exp2f(sc[rt][c][2] - m_[rt]);
        float e3 = __builtin_amdgcn_exp2f(sc[rt][c][3] - m_[rt]);
        lsum += (e0 + e1) + (e2 + e3);
        uint2 pk;
        pk.x = cvt_pk_bf16(e0, e1);
        pk.y = cvt_pk_bf16(e2, e3);
        int byteoff = (rt * 16 + llo) * 128 + ((c * 32 + lhi * 8) ^ ((llo & 7) << 4));
        *reinterpret_cast<uint2*>(PsW + byteoff) = pk;
      }
      l_[rt] = lsum;
    }

    short8 pf[2][2];
#pragma unroll
    for (int rt = 0; rt < 2; ++rt)
#pragma unroll
      for (int kc = 0; kc < 2; ++kc) {
        int byteoff = (rt * 16 + llo) * 128 + ((kc * 64 + lhi * 16) ^ ((llo & 7) << 4));
        pf[rt][kc] = *reinterpret_cast<const short8*>(PsW + byteoff);
      }
    __builtin_amdgcn_s_setprio(1);
#pragma unroll
    for (int dc = 0; dc < 8; ++dc) {
      int vrow = dc * 16 + llo;
      int bo0 = vrow * 128 + ((lhi * 16) ^ ((vrow & 7) << 4));
      int bo1 = vrow * 128 + ((64 + lhi * 16) ^ ((vrow & 7) << 4));
      short8 vf0 = *reinterpret_cast<const short8*>((const char*)&Vs[buf][0] + bo0);
      short8 vf1 = *reinterpret_cast<const short8*>((const char*)&Vs[buf][0] + bo1);
      acc[0][dc] = __builtin_amdgcn_mfma_f32_16x16x32_bf16(pf[0][0], vf0, acc[0][dc], 0, 0, 0);
      acc[1][dc] = __builtin_amdgcn_mfma_f32_16x16x32_bf16(pf[1][0], vf0, acc[1][dc], 0, 0, 0);
      acc[0][dc] = __builtin_amdgcn_mfma_f32_16x16x32_bf16(pf[0][1], vf1, acc[0][dc], 0, 0, 0);
      acc[1][dc] = __builtin_amdgcn_mfma_f32_16x16x32_bf16(pf[1][1], vf1, acc[1][dc], 0, 0, 0);
    }
    __builtin_amdgcn_s_setprio(0);
    __syncthreads();
    buf ^= 1;
  }

  // ---- epilogue: normalize, bounce through wave-private Ps (bf16, swizzled),
  //      then 16B-coalesced global stores ----
#pragma unroll
  for (int rt = 0; rt < 2; ++rt) {
    float t2 = l_[rt];
    t2 += __shfl_xor(t2, 16);
    t2 += __shfl_xor(t2, 32);
    float linv = 1.0f / t2;
    float lr[4];
#pragma unroll
    for (int r = 0; r < 4; ++r)
      lr[r] = __shfl(linv, (tid & 48) | (((tid >> 2) & 12) + r));
    // write normalized bf16 into PsW [16 rows][128 cols], 32B-granule swizzle by row>>2
    unsigned short* pw = (unsigned short*)PsW;
#pragma unroll
    for (int dc = 0; dc < 8; ++dc) {
      int pg = dc ^ lhi;   // row>>2 == lhi for rows lhi*4+r
#pragma unroll
      for (int r = 0; r < 4; ++r)
        pw[(lhi * 4 + r) * 128 + pg * 16 + llo] = f2bf(acc[rt][dc][r] * lr[r]);
    }
    // read back 16B chunks, un-swizzle, coalesced store
    int lane = tid & 63;
#pragma unroll
    for (int p = 0; p < 4; ++p) {
      int row = p * 4 + (lane >> 4);
      int ch = lane & 15;
      uint4 v = *reinterpret_cast<const uint4*>(PsW + row * 256 + ch * 16);
      int dc = (ch >> 1) ^ (row >> 2);
      int grow = qt * 256 + w * 32 + rt * 16 + row;
      *reinterpret_cast<uint4*>(attn + ((size_t)(b * 2048 + grow)) * 2048 +
                                h * 128 + dc * 16 + (ch & 1) * 8) = v;
    }
  }
}

extern "C" void kernel_launch(void* const* d_in, const int* in_sizes, int n_in,
                              void* d_out, int out_size, void* d_ws, size_t ws_size,
                              hipStream_t stream) {
  const float* query  = (const float*)d_in[0];
  const float* key_in = (const float*)d_in[1];
  const float* value  = (const float*)d_in[2];
  const float* Wq = (const float*)d_in[3];
  const float* bq = (const float*)d_in[4];
  const float* Wk = (const float*)d_in[5];
  const float* bk = (const float*)d_in[6];
  const float* Wv = (const float*)d_in[7];
  const float* bv = (const float*)d_in[8];
  const float* Wo = (const float*)d_in[9];
  const float* bo = (const float*)d_in[10];
  float* out = (float*)d_out;

  char* ws = (char*)d_ws;
  size_t off = 0;
  auto alloc = [&](size_t bytes) {
    char* p = ws + off;
    off += (bytes + 255) & ~(size_t)255;
    return p;
  };
  unsigned short* WqT  = (unsigned short*)alloc((size_t)E_ * E_ * 2);
  unsigned short* WkT  = (unsigned short*)alloc((size_t)KV_ * E_ * 2);
  unsigned short* WvT  = (unsigned short*)alloc((size_t)KV_ * E_ * 2);
  unsigned short* WoT  = (unsigned short*)alloc((size_t)E_ * E_ * 2);
  unsigned short* qb   = (unsigned short*)alloc((size_t)BS_ * E_ * 2);
  unsigned short* kb   = (unsigned short*)alloc((size_t)BS_ * KV_ * 2);
  unsigned short* vtb  = (unsigned short*)alloc((size_t)KV_ * BS_ * 2);
  unsigned short* attb = (unsigned short*)alloc((size_t)BS_ * E_ * 2);

  k_prep<<<10240, 256, 0, stream>>>(Wq, WqT, Wk, WkT, Wv, WvT, Wo, WoT);
  k_gemm_qkv<<<768, 256, 0, stream>>>(query, WqT, bq, qb, key_in, WkT, bk, kb,
                                      WvT, value, bv, vtb);
  k_attn<<<B_ * NH_ * (S_ / 256), 512, 0, stream>>>(qb, kb, vtb, attb);
  k_gemm_o<<<512, 256, 0, stream>>>(attb, WoT, bo, out);
}